// Round 2
// baseline (1685.748 us; speedup 1.0000x reference)
//
#include <hip/hip_runtime.h>
#include <math.h>

#define HF 64
#define LEAKY 0.2f

// ---------------- CSR build ----------------

__global__ void hist_kernel(const int* __restrict__ dst, int* __restrict__ cnt, int E) {
    int i = blockIdx.x * blockDim.x + threadIdx.x;
    int stride = gridDim.x * blockDim.x;
    for (; i < E; i += stride) atomicAdd(&cnt[dst[i]], 1);
}

__global__ void scan_kernel(const int* __restrict__ cnt, int* __restrict__ row_ptr,
                            int* __restrict__ cursor, int n) {
    __shared__ int sums[1024];
    int t = threadIdx.x;
    int chunk = (n + 1023) >> 10;
    int b0 = t * chunk;
    int b1 = min(b0 + chunk, n);
    int s = 0;
    for (int i = b0; i < b1; ++i) s += cnt[i];
    sums[t] = s;
    __syncthreads();
    for (int off = 1; off < 1024; off <<= 1) {
        int v = (t >= off) ? sums[t - off] : 0;
        __syncthreads();
        sums[t] += v;
        __syncthreads();
    }
    int run = (t == 0) ? 0 : sums[t - 1];
    for (int i = b0; i < b1; ++i) {
        int c = cnt[i];
        row_ptr[i] = run;
        cursor[i] = run;
        run += c;
    }
    if (t == 1023) row_ptr[n] = sums[1023];
}

__global__ void scatter_kernel(const int* __restrict__ src, const int* __restrict__ dst,
                               int* __restrict__ cursor, int* __restrict__ ssrc, int E) {
    int i = blockIdx.x * blockDim.x + threadIdx.x;
    int stride = gridDim.x * blockDim.x;
    for (; i < E; i += stride) {
        int p = atomicAdd(&cursor[dst[i]], 1);
        ssrc[p] = src[i];
    }
}

// ---------------- GEMM: H = X @ W, el = H a_l, er = H a_r ----------------
// 64-row tile per block, 256 threads, 4x4 register tile per thread.
// W transposed + XOR-swizzled in LDS; X read direct from global (L1 broadcast).

template <int K>
__global__ __launch_bounds__(256)
void gemm_kernel(const float* __restrict__ X, const float* __restrict__ W,
                 const float* __restrict__ al, const float* __restrict__ ar,
                 float* __restrict__ H, float* __restrict__ el, float* __restrict__ er,
                 int n) {
    __shared__ float Wt[64 * K];
    int tid = threadIdx.x;
    // stage W transposed, swizzled: word(c,k) = c*K + (k ^ ((c>>2 & 7)<<2))
    for (int f = tid; f < K * 64; f += 256) {
        int k = f >> 6, c = f & 63;
        Wt[c * K + (k ^ (((c >> 2) & 7) << 2))] = W[f];
    }
    __syncthreads();

    int tc = tid & 15, tr = tid >> 4;
    int r0 = blockIdx.x * 64 + tr * 4;
    const float* xbase = X + (size_t)r0 * K;

    bool rok[4];
#pragma unroll
    for (int r = 0; r < 4; ++r) rok[r] = (r0 + r) < n;

    float acc[4][4] = {};  // [row][col]

    for (int kq = 0; kq < K; kq += 4) {
        float4 xv[4];
#pragma unroll
        for (int r = 0; r < 4; ++r)
            xv[r] = rok[r] ? *(const float4*)(xbase + (size_t)r * K + kq)
                           : make_float4(0.f, 0.f, 0.f, 0.f);
#pragma unroll
        for (int i = 0; i < 4; ++i) {
            int c = tc * 4 + i;
            float4 wv = *(const float4*)(&Wt[c * K + (kq ^ (((c >> 2) & 7) << 2))]);
#pragma unroll
            for (int r = 0; r < 4; ++r) {
                acc[r][i] = fmaf(xv[r].x, wv.x, acc[r][i]);
                acc[r][i] = fmaf(xv[r].y, wv.y, acc[r][i]);
                acc[r][i] = fmaf(xv[r].z, wv.z, acc[r][i]);
                acc[r][i] = fmaf(xv[r].w, wv.w, acc[r][i]);
            }
        }
    }

    // epilogue: store H rows, fused el/er
    float alv[4], arv[4];
#pragma unroll
    for (int i = 0; i < 4; ++i) { alv[i] = al[tc * 4 + i]; arv[i] = ar[tc * 4 + i]; }

#pragma unroll
    for (int r = 0; r < 4; ++r) {
        if (!rok[r]) continue;
        *(float4*)(H + (size_t)(r0 + r) * HF + tc * 4) =
            make_float4(acc[r][0], acc[r][1], acc[r][2], acc[r][3]);
        float pl = acc[r][0] * alv[0] + acc[r][1] * alv[1] + acc[r][2] * alv[2] + acc[r][3] * alv[3];
        float pr = acc[r][0] * arv[0] + acc[r][1] * arv[1] + acc[r][2] * arv[2] + acc[r][3] * arv[3];
#pragma unroll
        for (int off = 1; off < 16; off <<= 1) {
            pl += __shfl_xor(pl, off);
            pr += __shfl_xor(pr, off);
        }
        if (tc == 0) { el[r0 + r] = pl; er[r0 + r] = pr; }
    }
}

// ---------------- Edge phase: softmax over incoming edges + aggregation ----------------

__global__ __launch_bounds__(256)
void edge_kernel(const int* __restrict__ row_ptr, const int* __restrict__ ssrc,
                 const float* __restrict__ el, const float* __restrict__ er,
                 const float* __restrict__ H, const float* __restrict__ b,
                 float* __restrict__ Y, int n) {
    int wave = threadIdx.x >> 6, lane = threadIdx.x & 63;
    int node = blockIdx.x * 4 + wave;
    if (node >= n) return;
    float bv = b[lane];
    int s0 = row_ptr[node], s1 = row_ptr[node + 1];
    int d = s1 - s0;
    float ern = er[node];
    float acc = 0.f, psum = 0.f;

    if (d <= 64) {
        // fast path: one edge per lane held in registers
        int sidx = 0;
        float e = -INFINITY;
        if (lane < d) {
            sidx = ssrc[s0 + lane];
            e = el[sidx] + ern;
            e = e > 0.f ? e : LEAKY * e;
        }
        float m = e;
#pragma unroll
        for (int off = 32; off; off >>= 1) m = fmaxf(m, __shfl_xor(m, off));
        float p = (lane < d) ? __expf(e - m) : 0.f;
        psum = p;
#pragma unroll
        for (int off = 32; off; off >>= 1) psum += __shfl_xor(psum, off);
#pragma unroll 4
        for (int jj = 0; jj < d; ++jj) {
            int s = __shfl(sidx, jj);
            float pj = __shfl(p, jj);
            acc = fmaf(pj, H[(size_t)s * HF + lane], acc);
        }
    } else {
        // fallback: two-pass
        float m = -INFINITY;
        for (int j = s0 + lane; j < s1; j += 64) {
            float e = el[ssrc[j]] + ern;
            e = e > 0.f ? e : LEAKY * e;
            m = fmaxf(m, e);
        }
#pragma unroll
        for (int off = 32; off; off >>= 1) m = fmaxf(m, __shfl_xor(m, off));
        for (int j = s0; j < s1; ++j) {
            int s = ssrc[j];
            float e = el[s] + ern;
            e = e > 0.f ? e : LEAKY * e;
            float p = __expf(e - m);
            psum += p;
            acc = fmaf(p, H[(size_t)s * HF + lane], acc);
        }
    }

    float o = d ? (acc / psum + bv) : bv;
    Y[(size_t)node * HF + lane] = o > 0.f ? o : 0.f;
}

// ---------------- launch ----------------

extern "C" void kernel_launch(void* const* d_in, const int* in_sizes, int n_in,
                              void* d_out, int out_size, void* d_ws, size_t ws_size,
                              hipStream_t stream) {
    const int N = in_sizes[0] / 128;
    const int E = in_sizes[1];

    const float* in_feat = (const float*)d_in[0];
    const int* src = (const int*)d_in[1];
    const int* dst = (const int*)d_in[2];
    const float* W1 = (const float*)d_in[3];
    const float* al1 = (const float*)d_in[4];
    const float* ar1 = (const float*)d_in[5];
    const float* b1 = (const float*)d_in[6];
    const float* W2 = (const float*)d_in[7];
    const float* al2 = (const float*)d_in[8];
    const float* ar2 = (const float*)d_in[9];
    const float* b2 = (const float*)d_in[10];
    const float* W3 = (const float*)d_in[11];
    const float* al3 = (const float*)d_in[12];
    const float* ar3 = (const float*)d_in[13];
    const float* b3 = (const float*)d_in[14];

    char* ws = (char*)d_ws;
    size_t off = 0;
    auto alloc = [&](size_t bytes) {
        void* p = ws + off;
        off += (bytes + 255) & ~(size_t)255;
        return p;
    };
    int* cnt = (int*)alloc((size_t)N * 4);
    int* row_ptr = (int*)alloc(((size_t)N + 1) * 4);
    int* cursor = (int*)alloc((size_t)N * 4);
    int* ssrc = (int*)alloc((size_t)E * 4);
    float* el = (float*)alloc((size_t)N * 4);
    float* er = (float*)alloc((size_t)N * 4);
    float* Hbuf = (float*)alloc((size_t)N * HF * 4);
    float* Ybuf = (float*)alloc((size_t)N * HF * 4);

    hipMemsetAsync(cnt, 0, (size_t)N * 4, stream);
    hist_kernel<<<2048, 256, 0, stream>>>(dst, cnt, E);
    scan_kernel<<<1, 1024, 0, stream>>>(cnt, row_ptr, cursor, N);
    scatter_kernel<<<2048, 256, 0, stream>>>(src, dst, cursor, ssrc, E);

    int gt = (N + 63) / 64;   // gemm tiles
    int ge = (N + 3) / 4;     // edge blocks (4 nodes/block)

    // layer 1
    gemm_kernel<128><<<gt, 256, 0, stream>>>(in_feat, W1, al1, ar1, Hbuf, el, er, N);
    edge_kernel<<<ge, 256, 0, stream>>>(row_ptr, ssrc, el, er, Hbuf, b1, Ybuf, N);
    // layer 2
    gemm_kernel<64><<<gt, 256, 0, stream>>>(Ybuf, W2, al2, ar2, Hbuf, el, er, N);
    edge_kernel<<<ge, 256, 0, stream>>>(row_ptr, ssrc, el, er, Hbuf, b2, Ybuf, N);
    // layer 3
    gemm_kernel<64><<<gt, 256, 0, stream>>>(Ybuf, W3, al3, ar3, Hbuf, el, er, N);
    edge_kernel<<<ge, 256, 0, stream>>>(row_ptr, ssrc, el, er, Hbuf, b3, (float*)d_out, N);
}

// Round 3
// 875.023 us; speedup vs baseline: 1.9265x; 1.9265x over previous
//
#include <hip/hip_runtime.h>
#include <math.h>

#define HF 64
#define LEAKY 0.2f

// ---------------- CSR build ----------------

__global__ void hist_kernel(const int* __restrict__ dst, int* __restrict__ cnt, int E) {
    int i = blockIdx.x * blockDim.x + threadIdx.x;
    int stride = gridDim.x * blockDim.x;
    for (; i < E; i += stride) atomicAdd(&cnt[dst[i]], 1);
}

__global__ void scan_kernel(const int* __restrict__ cnt, int* __restrict__ row_ptr,
                            int* __restrict__ cursor, int n) {
    __shared__ int sums[1024];
    int t = threadIdx.x;
    int chunk = (n + 1023) >> 10;
    int b0 = t * chunk;
    int b1 = min(b0 + chunk, n);
    int s = 0;
    for (int i = b0; i < b1; ++i) s += cnt[i];
    sums[t] = s;
    __syncthreads();
    for (int off = 1; off < 1024; off <<= 1) {
        int v = (t >= off) ? sums[t - off] : 0;
        __syncthreads();
        sums[t] += v;
        __syncthreads();
    }
    int run = (t == 0) ? 0 : sums[t - 1];
    for (int i = b0; i < b1; ++i) {
        int c = cnt[i];
        row_ptr[i] = run;
        cursor[i] = run;
        run += c;
    }
    if (t == 1023) row_ptr[n] = sums[1023];
}

__global__ void scatter_kernel(const int* __restrict__ src, const int* __restrict__ dst,
                               int* __restrict__ cursor, int* __restrict__ ssrc, int E) {
    int i = blockIdx.x * blockDim.x + threadIdx.x;
    int stride = gridDim.x * blockDim.x;
    for (; i < E; i += stride) {
        int p = atomicAdd(&cursor[dst[i]], 1);
        ssrc[p] = src[i];
    }
}

// ---------------- GEMM: H = X @ W, el = H a_l, er = H a_r ----------------
// 64-row tile per block, 256 threads, 4x4 register tile per thread.
// W transposed + XOR-swizzled in LDS; X read direct from global (L1 broadcast:
// 16 lanes share each address, each X word fetched once per block).
// __launch_bounds__(256,4) caps VGPR at 128; #pragma unroll 2 keeps only 8
// X-float4s in flight (round 2's full unroll hoisted ~256 floats -> spill).

template <int K>
__global__ __launch_bounds__(256, 4)
void gemm_kernel(const float* __restrict__ X, const float* __restrict__ W,
                 const float* __restrict__ al, const float* __restrict__ ar,
                 float* __restrict__ H, float* __restrict__ el, float* __restrict__ er,
                 int n) {
    __shared__ float Wt[64 * K];
    int tid = threadIdx.x;
    // stage W transposed, swizzled: word(c,k) = c*K + (k ^ ((c>>2 & 7)<<2))
    for (int f = tid; f < K * 64; f += 256) {
        int k = f >> 6, c = f & 63;
        Wt[c * K + (k ^ (((c >> 2) & 7) << 2))] = W[f];
    }
    __syncthreads();

    int tc = tid & 15, tr = tid >> 4;
    int r0 = blockIdx.x * 64 + tr * 4;
    const float* xbase = X + (size_t)r0 * K;

    bool rok[4];
#pragma unroll
    for (int r = 0; r < 4; ++r) rok[r] = (r0 + r) < n;

    float acc[4][4] = {};  // [row][col]

#pragma unroll 2
    for (int kq = 0; kq < K; kq += 4) {
        float4 xv[4];
#pragma unroll
        for (int r = 0; r < 4; ++r)
            xv[r] = rok[r] ? *(const float4*)(xbase + (size_t)r * K + kq)
                           : make_float4(0.f, 0.f, 0.f, 0.f);
#pragma unroll
        for (int i = 0; i < 4; ++i) {
            int c = tc * 4 + i;
            float4 wv = *(const float4*)(&Wt[c * K + (kq ^ (((c >> 2) & 7) << 2))]);
#pragma unroll
            for (int r = 0; r < 4; ++r) {
                acc[r][i] = fmaf(xv[r].x, wv.x, acc[r][i]);
                acc[r][i] = fmaf(xv[r].y, wv.y, acc[r][i]);
                acc[r][i] = fmaf(xv[r].z, wv.z, acc[r][i]);
                acc[r][i] = fmaf(xv[r].w, wv.w, acc[r][i]);
            }
        }
    }

    // epilogue: store H rows, fused el/er
    float alv[4], arv[4];
#pragma unroll
    for (int i = 0; i < 4; ++i) { alv[i] = al[tc * 4 + i]; arv[i] = ar[tc * 4 + i]; }

#pragma unroll
    for (int r = 0; r < 4; ++r) {
        if (!rok[r]) continue;
        *(float4*)(H + (size_t)(r0 + r) * HF + tc * 4) =
            make_float4(acc[r][0], acc[r][1], acc[r][2], acc[r][3]);
        float pl = acc[r][0] * alv[0] + acc[r][1] * alv[1] + acc[r][2] * alv[2] + acc[r][3] * alv[3];
        float pr = acc[r][0] * arv[0] + acc[r][1] * arv[1] + acc[r][2] * arv[2] + acc[r][3] * arv[3];
#pragma unroll
        for (int off = 1; off < 16; off <<= 1) {
            pl += __shfl_xor(pl, off);
            pr += __shfl_xor(pr, off);
        }
        if (tc == 0) { el[r0 + r] = pl; er[r0 + r] = pr; }
    }
}

// ---------------- Edge phase: softmax over incoming edges + aggregation ----------------

__global__ __launch_bounds__(256)
void edge_kernel(const int* __restrict__ row_ptr, const int* __restrict__ ssrc,
                 const float* __restrict__ el, const float* __restrict__ er,
                 const float* __restrict__ H, const float* __restrict__ b,
                 float* __restrict__ Y, int n) {
    int wave = threadIdx.x >> 6, lane = threadIdx.x & 63;
    int node = blockIdx.x * 4 + wave;
    if (node >= n) return;
    float bv = b[lane];
    int s0 = row_ptr[node], s1 = row_ptr[node + 1];
    int d = s1 - s0;
    float ern = er[node];
    float acc = 0.f, psum = 0.f;

    if (d <= 64) {
        // fast path: one edge per lane held in registers
        int sidx = 0;
        float e = -INFINITY;
        if (lane < d) {
            sidx = ssrc[s0 + lane];
            e = el[sidx] + ern;
            e = e > 0.f ? e : LEAKY * e;
        }
        float m = e;
#pragma unroll
        for (int off = 32; off; off >>= 1) m = fmaxf(m, __shfl_xor(m, off));
        float p = (lane < d) ? __expf(e - m) : 0.f;
        psum = p;
#pragma unroll
        for (int off = 32; off; off >>= 1) psum += __shfl_xor(psum, off);
#pragma unroll 4
        for (int jj = 0; jj < d; ++jj) {
            int s = __shfl(sidx, jj);
            float pj = __shfl(p, jj);
            acc = fmaf(pj, H[(size_t)s * HF + lane], acc);
        }
    } else {
        // fallback: two-pass
        float m = -INFINITY;
        for (int j = s0 + lane; j < s1; j += 64) {
            float e = el[ssrc[j]] + ern;
            e = e > 0.f ? e : LEAKY * e;
            m = fmaxf(m, e);
        }
#pragma unroll
        for (int off = 32; off; off >>= 1) m = fmaxf(m, __shfl_xor(m, off));
        for (int j = s0; j < s1; ++j) {
            int s = ssrc[j];
            float e = el[s] + ern;
            e = e > 0.f ? e : LEAKY * e;
            float p = __expf(e - m);
            psum += p;
            acc = fmaf(p, H[(size_t)s * HF + lane], acc);
        }
    }

    float o = d ? (acc / psum + bv) : bv;
    Y[(size_t)node * HF + lane] = o > 0.f ? o : 0.f;
}

// ---------------- launch ----------------

extern "C" void kernel_launch(void* const* d_in, const int* in_sizes, int n_in,
                              void* d_out, int out_size, void* d_ws, size_t ws_size,
                              hipStream_t stream) {
    const int N = in_sizes[0] / 128;
    const int E = in_sizes[1];

    const float* in_feat = (const float*)d_in[0];
    const int* src = (const int*)d_in[1];
    const int* dst = (const int*)d_in[2];
    const float* W1 = (const float*)d_in[3];
    const float* al1 = (const float*)d_in[4];
    const float* ar1 = (const float*)d_in[5];
    const float* b1 = (const float*)d_in[6];
    const float* W2 = (const float*)d_in[7];
    const float* al2 = (const float*)d_in[8];
    const float* ar2 = (const float*)d_in[9];
    const float* b2 = (const float*)d_in[10];
    const float* W3 = (const float*)d_in[11];
    const float* al3 = (const float*)d_in[12];
    const float* ar3 = (const float*)d_in[13];
    const float* b3 = (const float*)d_in[14];

    char* ws = (char*)d_ws;
    size_t off = 0;
    auto alloc = [&](size_t bytes) {
        void* p = ws + off;
        off += (bytes + 255) & ~(size_t)255;
        return p;
    };
    int* cnt = (int*)alloc((size_t)N * 4);
    int* row_ptr = (int*)alloc(((size_t)N + 1) * 4);
    int* cursor = (int*)alloc((size_t)N * 4);
    int* ssrc = (int*)alloc((size_t)E * 4);
    float* el = (float*)alloc((size_t)N * 4);
    float* er = (float*)alloc((size_t)N * 4);
    float* Hbuf = (float*)alloc((size_t)N * HF * 4);
    float* Ybuf = (float*)alloc((size_t)N * HF * 4);

    hipMemsetAsync(cnt, 0, (size_t)N * 4, stream);
    hist_kernel<<<2048, 256, 0, stream>>>(dst, cnt, E);
    scan_kernel<<<1, 1024, 0, stream>>>(cnt, row_ptr, cursor, N);
    scatter_kernel<<<2048, 256, 0, stream>>>(src, dst, cursor, ssrc, E);

    int gt = (N + 63) / 64;   // gemm tiles
    int ge = (N + 3) / 4;     // edge blocks (4 nodes/block)

    // layer 1
    gemm_kernel<128><<<gt, 256, 0, stream>>>(in_feat, W1, al1, ar1, Hbuf, el, er, N);
    edge_kernel<<<ge, 256, 0, stream>>>(row_ptr, ssrc, el, er, Hbuf, b1, Ybuf, N);
    // layer 2
    gemm_kernel<64><<<gt, 256, 0, stream>>>(Ybuf, W2, al2, ar2, Hbuf, el, er, N);
    edge_kernel<<<ge, 256, 0, stream>>>(row_ptr, ssrc, el, er, Hbuf, b2, Ybuf, N);
    // layer 3
    gemm_kernel<64><<<gt, 256, 0, stream>>>(Ybuf, W3, al3, ar3, Hbuf, el, er, N);
    edge_kernel<<<ge, 256, 0, stream>>>(row_ptr, ssrc, el, er, Hbuf, b3, (float*)d_out, N);
}

// Round 4
// 661.445 us; speedup vs baseline: 2.5486x; 1.3229x over previous
//
#include <hip/hip_runtime.h>
#include <math.h>

#define HF 64
#define LEAKY 0.2f
#define SCAN_BLOCKS 256
#define SCAN_THREADS 256

// ---------------- CSR build ----------------

__global__ void hist_kernel(const int* __restrict__ dst, int* __restrict__ cnt, int E) {
    int i = blockIdx.x * blockDim.x + threadIdx.x;
    int stride = gridDim.x * blockDim.x;
    for (; i < E; i += stride) atomicAdd(&cnt[dst[i]], 1);
}

// phase 1: per-block chunk sums
__global__ __launch_bounds__(SCAN_THREADS)
void scan_partial(const int* __restrict__ cnt, int* __restrict__ bsum, int n) {
    int chunk = (n + SCAN_BLOCKS - 1) / SCAN_BLOCKS;
    int b0 = blockIdx.x * chunk, b1 = min(b0 + chunk, n);
    int s = 0;
    for (int i = b0 + threadIdx.x; i < b1; i += SCAN_THREADS) s += cnt[i];
#pragma unroll
    for (int off = 32; off; off >>= 1) s += __shfl_xor(s, off);
    __shared__ int wsum[4];
    int wave = threadIdx.x >> 6, lane = threadIdx.x & 63;
    if (lane == 0) wsum[wave] = s;
    __syncthreads();
    if (threadIdx.x == 0) bsum[blockIdx.x] = wsum[0] + wsum[1] + wsum[2] + wsum[3];
}

// phase 2: exclusive scan of the 256 block sums
__global__ __launch_bounds__(SCAN_BLOCKS)
void scan_bsums(const int* __restrict__ bsum, int* __restrict__ boff, int* __restrict__ total) {
    __shared__ int tmp[SCAN_BLOCKS];
    int t = threadIdx.x;
    int v = bsum[t];
    tmp[t] = v;
    __syncthreads();
    for (int off = 1; off < SCAN_BLOCKS; off <<= 1) {
        int u = (t >= off) ? tmp[t - off] : 0;
        __syncthreads();
        tmp[t] += u;
        __syncthreads();
    }
    boff[t] = tmp[t] - v;
    if (t == SCAN_BLOCKS - 1) total[0] = tmp[t];
}

// phase 3: per-chunk exclusive scan with block offset
__global__ __launch_bounds__(SCAN_THREADS)
void scan_final(const int* __restrict__ cnt, const int* __restrict__ boff,
                const int* __restrict__ total, int* __restrict__ row_ptr,
                int* __restrict__ cursor, int n) {
    int chunk = (n + SCAN_BLOCKS - 1) / SCAN_BLOCKS;
    int b0 = blockIdx.x * chunk, b1 = min(b0 + chunk, n);
    __shared__ int tile[SCAN_THREADS];
    int carry = boff[blockIdx.x];
    for (int base = b0; base < b1; base += SCAN_THREADS) {
        int i = base + threadIdx.x;
        int v = (i < b1) ? cnt[i] : 0;
        tile[threadIdx.x] = v;
        __syncthreads();
        for (int off = 1; off < SCAN_THREADS; off <<= 1) {
            int u = (threadIdx.x >= off) ? tile[threadIdx.x - off] : 0;
            __syncthreads();
            tile[threadIdx.x] += u;
            __syncthreads();
        }
        if (i < b1) {
            int excl = carry + tile[threadIdx.x] - v;
            row_ptr[i] = excl;
            cursor[i] = excl;
        }
        carry += tile[SCAN_THREADS - 1];
        __syncthreads();
    }
    if (blockIdx.x == SCAN_BLOCKS - 1 && threadIdx.x == 0) row_ptr[n] = total[0];
}

__global__ void scatter_kernel(const int* __restrict__ src, const int* __restrict__ dst,
                               int* __restrict__ cursor, int* __restrict__ ssrc, int E) {
    int i = blockIdx.x * blockDim.x + threadIdx.x;
    int stride = gridDim.x * blockDim.x;
    for (; i < E; i += stride) {
        int p = atomicAdd(&cursor[dst[i]], 1);
        ssrc[p] = src[i];
    }
}

// ---------------- GEMM: H = X @ W, el = H a_l, er = H a_r ----------------
// 64-row tile per block, 256 threads, 4x4 register tile per thread.
// W transposed + XOR-swizzled in LDS; X read direct from global (L1 broadcast:
// 16 lanes share each address, each X word fetched once per block).
// __launch_bounds__(256,4) caps VGPR at 128; #pragma unroll 2 keeps only 8
// X-float4s in flight (round 2's full unroll hoisted ~256 floats -> spill).

template <int K>
__global__ __launch_bounds__(256, 4)
void gemm_kernel(const float* __restrict__ X, const float* __restrict__ W,
                 const float* __restrict__ al, const float* __restrict__ ar,
                 float* __restrict__ H, float* __restrict__ el, float* __restrict__ er,
                 int n) {
    __shared__ float Wt[64 * K];
    int tid = threadIdx.x;
    for (int f = tid; f < K * 64; f += 256) {
        int k = f >> 6, c = f & 63;
        Wt[c * K + (k ^ (((c >> 2) & 7) << 2))] = W[f];
    }
    __syncthreads();

    int tc = tid & 15, tr = tid >> 4;
    int r0 = blockIdx.x * 64 + tr * 4;
    const float* xbase = X + (size_t)r0 * K;

    bool rok[4];
#pragma unroll
    for (int r = 0; r < 4; ++r) rok[r] = (r0 + r) < n;

    float acc[4][4] = {};

#pragma unroll 2
    for (int kq = 0; kq < K; kq += 4) {
        float4 xv[4];
#pragma unroll
        for (int r = 0; r < 4; ++r)
            xv[r] = rok[r] ? *(const float4*)(xbase + (size_t)r * K + kq)
                           : make_float4(0.f, 0.f, 0.f, 0.f);
#pragma unroll
        for (int i = 0; i < 4; ++i) {
            int c = tc * 4 + i;
            float4 wv = *(const float4*)(&Wt[c * K + (kq ^ (((c >> 2) & 7) << 2))]);
#pragma unroll
            for (int r = 0; r < 4; ++r) {
                acc[r][i] = fmaf(xv[r].x, wv.x, acc[r][i]);
                acc[r][i] = fmaf(xv[r].y, wv.y, acc[r][i]);
                acc[r][i] = fmaf(xv[r].z, wv.z, acc[r][i]);
                acc[r][i] = fmaf(xv[r].w, wv.w, acc[r][i]);
            }
        }
    }

    float alv[4], arv[4];
#pragma unroll
    for (int i = 0; i < 4; ++i) { alv[i] = al[tc * 4 + i]; arv[i] = ar[tc * 4 + i]; }

#pragma unroll
    for (int r = 0; r < 4; ++r) {
        if (!rok[r]) continue;
        *(float4*)(H + (size_t)(r0 + r) * HF + tc * 4) =
            make_float4(acc[r][0], acc[r][1], acc[r][2], acc[r][3]);
        float pl = acc[r][0] * alv[0] + acc[r][1] * alv[1] + acc[r][2] * alv[2] + acc[r][3] * alv[3];
        float pr = acc[r][0] * arv[0] + acc[r][1] * arv[1] + acc[r][2] * arv[2] + acc[r][3] * arv[3];
#pragma unroll
        for (int off = 1; off < 16; off <<= 1) {
            pl += __shfl_xor(pl, off);
            pr += __shfl_xor(pr, off);
        }
        if (tc == 0) { el[r0 + r] = pl; er[r0 + r] = pr; }
    }
}

// ---------------- Edge phase: softmax over incoming edges + aggregation ----------------

__global__ __launch_bounds__(256)
void edge_kernel(const int* __restrict__ row_ptr, const int* __restrict__ ssrc,
                 const float* __restrict__ el, const float* __restrict__ er,
                 const float* __restrict__ H, const float* __restrict__ b,
                 float* __restrict__ Y, int n) {
    int wave = threadIdx.x >> 6, lane = threadIdx.x & 63;
    int node = blockIdx.x * 4 + wave;
    if (node >= n) return;
    float bv = b[lane];
    int s0 = row_ptr[node], s1 = row_ptr[node + 1];
    int d = s1 - s0;
    float ern = er[node];
    float acc = 0.f, psum = 0.f;

    if (d <= 64) {
        int sidx = 0;
        float e = -INFINITY;
        if (lane < d) {
            sidx = ssrc[s0 + lane];
            e = el[sidx] + ern;
            e = e > 0.f ? e : LEAKY * e;
        }
        float m = e;
#pragma unroll
        for (int off = 32; off; off >>= 1) m = fmaxf(m, __shfl_xor(m, off));
        float p = (lane < d) ? __expf(e - m) : 0.f;
        psum = p;
#pragma unroll
        for (int off = 32; off; off >>= 1) psum += __shfl_xor(psum, off);
#pragma unroll 4
        for (int jj = 0; jj < d; ++jj) {
            int s = __shfl(sidx, jj);
            float pj = __shfl(p, jj);
            acc = fmaf(pj, H[(size_t)s * HF + lane], acc);
        }
    } else {
        float m = -INFINITY;
        for (int j = s0 + lane; j < s1; j += 64) {
            float e = el[ssrc[j]] + ern;
            e = e > 0.f ? e : LEAKY * e;
            m = fmaxf(m, e);
        }
#pragma unroll
        for (int off = 32; off; off >>= 1) m = fmaxf(m, __shfl_xor(m, off));
        for (int j = s0; j < s1; ++j) {
            int s = ssrc[j];
            float e = el[s] + ern;
            e = e > 0.f ? e : LEAKY * e;
            float p = __expf(e - m);
            psum += p;
            acc = fmaf(p, H[(size_t)s * HF + lane], acc);
        }
    }

    float o = d ? (acc / psum + bv) : bv;
    Y[(size_t)node * HF + lane] = o > 0.f ? o : 0.f;
}

// ---------------- launch ----------------

extern "C" void kernel_launch(void* const* d_in, const int* in_sizes, int n_in,
                              void* d_out, int out_size, void* d_ws, size_t ws_size,
                              hipStream_t stream) {
    const int N = in_sizes[0] / 128;
    const int E = in_sizes[1];

    const float* in_feat = (const float*)d_in[0];
    const int* src = (const int*)d_in[1];
    const int* dst = (const int*)d_in[2];
    const float* W1 = (const float*)d_in[3];
    const float* al1 = (const float*)d_in[4];
    const float* ar1 = (const float*)d_in[5];
    const float* b1 = (const float*)d_in[6];
    const float* W2 = (const float*)d_in[7];
    const float* al2 = (const float*)d_in[8];
    const float* ar2 = (const float*)d_in[9];
    const float* b2 = (const float*)d_in[10];
    const float* W3 = (const float*)d_in[11];
    const float* al3 = (const float*)d_in[12];
    const float* ar3 = (const float*)d_in[13];
    const float* b3 = (const float*)d_in[14];

    char* ws = (char*)d_ws;
    size_t off = 0;
    auto alloc = [&](size_t bytes) {
        void* p = ws + off;
        off += (bytes + 255) & ~(size_t)255;
        return p;
    };
    int* cnt = (int*)alloc((size_t)N * 4);
    int* row_ptr = (int*)alloc(((size_t)N + 1) * 4);
    int* cursor = (int*)alloc((size_t)N * 4);
    int* ssrc = (int*)alloc((size_t)E * 4);
    float* el = (float*)alloc((size_t)N * 4);
    float* er = (float*)alloc((size_t)N * 4);
    float* Hbuf = (float*)alloc((size_t)N * HF * 4);
    float* Ybuf = (float*)alloc((size_t)N * HF * 4);
    int* bsum = (int*)alloc(SCAN_BLOCKS * 4);
    int* boff = (int*)alloc(SCAN_BLOCKS * 4);
    int* total = (int*)alloc(4);

    hipMemsetAsync(cnt, 0, (size_t)N * 4, stream);
    hist_kernel<<<2048, 256, 0, stream>>>(dst, cnt, E);
    scan_partial<<<SCAN_BLOCKS, SCAN_THREADS, 0, stream>>>(cnt, bsum, N);
    scan_bsums<<<1, SCAN_BLOCKS, 0, stream>>>(bsum, boff, total);
    scan_final<<<SCAN_BLOCKS, SCAN_THREADS, 0, stream>>>(cnt, boff, total, row_ptr, cursor, N);
    scatter_kernel<<<2048, 256, 0, stream>>>(src, dst, cursor, ssrc, E);

    int gt = (N + 63) / 64;   // gemm tiles
    int ge = (N + 3) / 4;     // edge blocks (4 nodes/block)

    // layer 1
    gemm_kernel<128><<<gt, 256, 0, stream>>>(in_feat, W1, al1, ar1, Hbuf, el, er, N);
    edge_kernel<<<ge, 256, 0, stream>>>(row_ptr, ssrc, el, er, Hbuf, b1, Ybuf, N);
    // layer 2
    gemm_kernel<64><<<gt, 256, 0, stream>>>(Ybuf, W2, al2, ar2, Hbuf, el, er, N);
    edge_kernel<<<ge, 256, 0, stream>>>(row_ptr, ssrc, el, er, Hbuf, b2, Ybuf, N);
    // layer 3
    gemm_kernel<64><<<gt, 256, 0, stream>>>(Ybuf, W3, al3, ar3, Hbuf, el, er, N);
    edge_kernel<<<ge, 256, 0, stream>>>(row_ptr, ssrc, el, er, Hbuf, b3, (float*)d_out, N);
}

// Round 5
// 449.734 us; speedup vs baseline: 3.7483x; 1.4707x over previous
//
#include <hip/hip_runtime.h>
#include <math.h>

#define HF 64
#define LEAKY 0.2f
#define SCAN_BLOCKS 256
#define SCAN_THREADS 256

// ---------------- CSR build ----------------
// hist also records each edge's rank among same-dst edges -> scatter needs no atomic.

__global__ void hist_kernel(const int* __restrict__ dst, int* __restrict__ cnt,
                            int* __restrict__ rank, int E) {
    int i = blockIdx.x * blockDim.x + threadIdx.x;
    int stride = gridDim.x * blockDim.x;
    for (; i < E; i += stride) rank[i] = atomicAdd(&cnt[dst[i]], 1);
}

// phase 1: per-block chunk sums
__global__ __launch_bounds__(SCAN_THREADS)
void scan_partial(const int* __restrict__ cnt, int* __restrict__ bsum, int n) {
    int chunk = (n + SCAN_BLOCKS - 1) / SCAN_BLOCKS;
    int b0 = blockIdx.x * chunk, b1 = min(b0 + chunk, n);
    int s = 0;
    for (int i = b0 + threadIdx.x; i < b1; i += SCAN_THREADS) s += cnt[i];
#pragma unroll
    for (int off = 32; off; off >>= 1) s += __shfl_xor(s, off);
    __shared__ int wsum[4];
    int wave = threadIdx.x >> 6, lane = threadIdx.x & 63;
    if (lane == 0) wsum[wave] = s;
    __syncthreads();
    if (threadIdx.x == 0) bsum[blockIdx.x] = wsum[0] + wsum[1] + wsum[2] + wsum[3];
}

// phase 2: exclusive scan of the 256 block sums
__global__ __launch_bounds__(SCAN_BLOCKS)
void scan_bsums(const int* __restrict__ bsum, int* __restrict__ boff, int* __restrict__ total) {
    __shared__ int tmp[SCAN_BLOCKS];
    int t = threadIdx.x;
    int v = bsum[t];
    tmp[t] = v;
    __syncthreads();
    for (int off = 1; off < SCAN_BLOCKS; off <<= 1) {
        int u = (t >= off) ? tmp[t - off] : 0;
        __syncthreads();
        tmp[t] += u;
        __syncthreads();
    }
    boff[t] = tmp[t] - v;
    if (t == SCAN_BLOCKS - 1) total[0] = tmp[t];
}

// phase 3: per-chunk exclusive scan with block offset -> row_ptr
__global__ __launch_bounds__(SCAN_THREADS)
void scan_final(const int* __restrict__ cnt, const int* __restrict__ boff,
                const int* __restrict__ total, int* __restrict__ row_ptr, int n) {
    int chunk = (n + SCAN_BLOCKS - 1) / SCAN_BLOCKS;
    int b0 = blockIdx.x * chunk, b1 = min(b0 + chunk, n);
    __shared__ int tile[SCAN_THREADS];
    int carry = boff[blockIdx.x];
    for (int base = b0; base < b1; base += SCAN_THREADS) {
        int i = base + threadIdx.x;
        int v = (i < b1) ? cnt[i] : 0;
        tile[threadIdx.x] = v;
        __syncthreads();
        for (int off = 1; off < SCAN_THREADS; off <<= 1) {
            int u = (threadIdx.x >= off) ? tile[threadIdx.x - off] : 0;
            __syncthreads();
            tile[threadIdx.x] += u;
            __syncthreads();
        }
        if (i < b1) row_ptr[i] = carry + tile[threadIdx.x] - v;
        carry += tile[SCAN_THREADS - 1];
        __syncthreads();
    }
    if (blockIdx.x == SCAN_BLOCKS - 1 && threadIdx.x == 0) row_ptr[n] = total[0];
}

// atomic-free scatter: position fully determined by row_ptr + precomputed rank
__global__ void scatter_kernel(const int* __restrict__ src, const int* __restrict__ dst,
                               const int* __restrict__ rank, const int* __restrict__ row_ptr,
                               int* __restrict__ ssrc, int E) {
    int i = blockIdx.x * blockDim.x + threadIdx.x;
    int stride = gridDim.x * blockDim.x;
    for (; i < E; i += stride) {
        ssrc[row_ptr[dst[i]] + rank[i]] = src[i];
    }
}

// ---------------- GEMM: H = X @ W, el = H a_l, er = H a_r ----------------
// 64-row tile per block, 256 threads, 4x4 register tile per thread.
// W transposed + XOR-swizzled in LDS; X read direct from global (L1 broadcast).
// __launch_bounds__(256,4) caps VGPR at 128; #pragma unroll 2 keeps only 8
// X-float4s in flight (round 2's full unroll hoisted ~256 floats -> spill).

template <int K>
__global__ __launch_bounds__(256, 4)
void gemm_kernel(const float* __restrict__ X, const float* __restrict__ W,
                 const float* __restrict__ al, const float* __restrict__ ar,
                 float* __restrict__ H, float* __restrict__ el, float* __restrict__ er,
                 int n) {
    __shared__ float Wt[64 * K];
    int tid = threadIdx.x;
    for (int f = tid; f < K * 64; f += 256) {
        int k = f >> 6, c = f & 63;
        Wt[c * K + (k ^ (((c >> 2) & 7) << 2))] = W[f];
    }
    __syncthreads();

    int tc = tid & 15, tr = tid >> 4;
    int r0 = blockIdx.x * 64 + tr * 4;
    const float* xbase = X + (size_t)r0 * K;

    bool rok[4];
#pragma unroll
    for (int r = 0; r < 4; ++r) rok[r] = (r0 + r) < n;

    float acc[4][4] = {};

#pragma unroll 2
    for (int kq = 0; kq < K; kq += 4) {
        float4 xv[4];
#pragma unroll
        for (int r = 0; r < 4; ++r)
            xv[r] = rok[r] ? *(const float4*)(xbase + (size_t)r * K + kq)
                           : make_float4(0.f, 0.f, 0.f, 0.f);
#pragma unroll
        for (int i = 0; i < 4; ++i) {
            int c = tc * 4 + i;
            float4 wv = *(const float4*)(&Wt[c * K + (kq ^ (((c >> 2) & 7) << 2))]);
#pragma unroll
            for (int r = 0; r < 4; ++r) {
                acc[r][i] = fmaf(xv[r].x, wv.x, acc[r][i]);
                acc[r][i] = fmaf(xv[r].y, wv.y, acc[r][i]);
                acc[r][i] = fmaf(xv[r].z, wv.z, acc[r][i]);
                acc[r][i] = fmaf(xv[r].w, wv.w, acc[r][i]);
            }
        }
    }

    float alv[4], arv[4];
#pragma unroll
    for (int i = 0; i < 4; ++i) { alv[i] = al[tc * 4 + i]; arv[i] = ar[tc * 4 + i]; }

#pragma unroll
    for (int r = 0; r < 4; ++r) {
        if (!rok[r]) continue;
        *(float4*)(H + (size_t)(r0 + r) * HF + tc * 4) =
            make_float4(acc[r][0], acc[r][1], acc[r][2], acc[r][3]);
        float pl = acc[r][0] * alv[0] + acc[r][1] * alv[1] + acc[r][2] * alv[2] + acc[r][3] * alv[3];
        float pr = acc[r][0] * arv[0] + acc[r][1] * arv[1] + acc[r][2] * arv[2] + acc[r][3] * arv[3];
#pragma unroll
        for (int off = 1; off < 16; off <<= 1) {
            pl += __shfl_xor(pl, off);
            pr += __shfl_xor(pr, off);
        }
        if (tc == 0) { el[r0 + r] = pl; er[r0 + r] = pr; }
    }
}

// ---------------- Edge phase: softmax over incoming edges + aggregation ----------------
// Wave = 4 groups x 16 lanes. Group g handles edge j = 4t+g, loading H rows as
// float4 (16 lanes x 16B = full 256B row). Cross-group merge = 2 float4 shfl_xor.

__global__ __launch_bounds__(256)
void edge_kernel(const int* __restrict__ row_ptr, const int* __restrict__ ssrc,
                 const float* __restrict__ el, const float* __restrict__ er,
                 const float* __restrict__ H, const float* __restrict__ b,
                 float* __restrict__ Y, int n) {
    int wave = threadIdx.x >> 6, lane = threadIdx.x & 63;
    int node = blockIdx.x * 4 + wave;
    if (node >= n) return;
    int g = lane >> 4, fl = lane & 15;
    int s0 = row_ptr[node], s1 = row_ptr[node + 1];
    int d = s1 - s0;
    float ern = er[node];
    const float4* H4 = (const float4*)H;

    if (d <= 64) {
        // one edge per lane in registers
        int sidx = 0;
        float e = -INFINITY;
        if (lane < d) {
            sidx = ssrc[s0 + lane];
            e = el[sidx] + ern;
            e = e > 0.f ? e : LEAKY * e;
        }
        float m = e;
#pragma unroll
        for (int off = 32; off; off >>= 1) m = fmaxf(m, __shfl_xor(m, off));
        float p = (lane < d) ? __expf(e - m) : 0.f;
        float psum = p;
#pragma unroll
        for (int off = 32; off; off >>= 1) psum += __shfl_xor(psum, off);

        float4 acc = make_float4(0.f, 0.f, 0.f, 0.f);
        int nt = (d + 3) >> 2;
        for (int t = 0; t < nt; ++t) {
            int j = t * 4 + g;            // per-lane edge index
            int s = __shfl(sidx, j);      // lanes j>=d give sidx=0 (valid row), p=0
            float pj = __shfl(p, j);
            float4 v = H4[(size_t)s * 16 + fl];
            acc.x = fmaf(pj, v.x, acc.x);
            acc.y = fmaf(pj, v.y, acc.y);
            acc.z = fmaf(pj, v.z, acc.z);
            acc.w = fmaf(pj, v.w, acc.w);
        }
        // merge the 4 groups (lanes ^16, ^32)
#pragma unroll
        for (int off = 16; off <= 32; off <<= 1) {
            acc.x += __shfl_xor(acc.x, off);
            acc.y += __shfl_xor(acc.y, off);
            acc.z += __shfl_xor(acc.z, off);
            acc.w += __shfl_xor(acc.w, off);
        }
        float inv = d ? 1.f / psum : 0.f;
        float4 bv = ((const float4*)b)[fl];
        float4 o;
        o.x = fmaf(acc.x, inv, bv.x);
        o.y = fmaf(acc.y, inv, bv.y);
        o.z = fmaf(acc.z, inv, bv.z);
        o.w = fmaf(acc.w, inv, bv.w);
        o.x = o.x > 0.f ? o.x : 0.f;
        o.y = o.y > 0.f ? o.y : 0.f;
        o.z = o.z > 0.f ? o.z : 0.f;
        o.w = o.w > 0.f ? o.w : 0.f;
        if (g == 0) ((float4*)Y)[(size_t)node * 16 + fl] = o;
    } else {
        // fallback: two-pass, lane = feature
        float m = -INFINITY;
        for (int j = s0 + lane; j < s1; j += 64) {
            float e = el[ssrc[j]] + ern;
            e = e > 0.f ? e : LEAKY * e;
            m = fmaxf(m, e);
        }
#pragma unroll
        for (int off = 32; off; off >>= 1) m = fmaxf(m, __shfl_xor(m, off));
        float acc = 0.f, psum = 0.f;
        for (int j = s0; j < s1; ++j) {
            int s = ssrc[j];
            float e = el[s] + ern;
            e = e > 0.f ? e : LEAKY * e;
            float p = __expf(e - m);
            psum += p;
            acc = fmaf(p, H[(size_t)s * HF + lane], acc);
        }
        float o = acc / psum + b[lane];
        Y[(size_t)node * HF + lane] = o > 0.f ? o : 0.f;
    }
}

// ---------------- launch ----------------

extern "C" void kernel_launch(void* const* d_in, const int* in_sizes, int n_in,
                              void* d_out, int out_size, void* d_ws, size_t ws_size,
                              hipStream_t stream) {
    const int N = in_sizes[0] / 128;
    const int E = in_sizes[1];

    const float* in_feat = (const float*)d_in[0];
    const int* src = (const int*)d_in[1];
    const int* dst = (const int*)d_in[2];
    const float* W1 = (const float*)d_in[3];
    const float* al1 = (const float*)d_in[4];
    const float* ar1 = (const float*)d_in[5];
    const float* b1 = (const float*)d_in[6];
    const float* W2 = (const float*)d_in[7];
    const float* al2 = (const float*)d_in[8];
    const float* ar2 = (const float*)d_in[9];
    const float* b2 = (const float*)d_in[10];
    const float* W3 = (const float*)d_in[11];
    const float* al3 = (const float*)d_in[12];
    const float* ar3 = (const float*)d_in[13];
    const float* b3 = (const float*)d_in[14];

    char* ws = (char*)d_ws;
    size_t off = 0;
    auto alloc = [&](size_t bytes) {
        void* p = ws + off;
        off += (bytes + 255) & ~(size_t)255;
        return p;
    };
    int* cnt = (int*)alloc((size_t)N * 4);
    int* row_ptr = (int*)alloc(((size_t)N + 1) * 4);
    int* rank = (int*)alloc((size_t)E * 4);
    int* ssrc = (int*)alloc((size_t)E * 4);
    float* el = (float*)alloc((size_t)N * 4);
    float* er = (float*)alloc((size_t)N * 4);
    float* Hbuf = (float*)alloc((size_t)N * HF * 4);
    float* Ybuf = (float*)alloc((size_t)N * HF * 4);
    int* bsum = (int*)alloc(SCAN_BLOCKS * 4);
    int* boff = (int*)alloc(SCAN_BLOCKS * 4);
    int* total = (int*)alloc(4);

    hipMemsetAsync(cnt, 0, (size_t)N * 4, stream);
    hist_kernel<<<2048, 256, 0, stream>>>(dst, cnt, rank, E);
    scan_partial<<<SCAN_BLOCKS, SCAN_THREADS, 0, stream>>>(cnt, bsum, N);
    scan_bsums<<<1, SCAN_BLOCKS, 0, stream>>>(bsum, boff, total);
    scan_final<<<SCAN_BLOCKS, SCAN_THREADS, 0, stream>>>(cnt, boff, total, row_ptr, N);
    scatter_kernel<<<2048, 256, 0, stream>>>(src, dst, rank, row_ptr, ssrc, E);

    int gt = (N + 63) / 64;   // gemm tiles
    int ge = (N + 3) / 4;     // edge blocks (4 nodes/block)

    // layer 1
    gemm_kernel<128><<<gt, 256, 0, stream>>>(in_feat, W1, al1, ar1, Hbuf, el, er, N);
    edge_kernel<<<ge, 256, 0, stream>>>(row_ptr, ssrc, el, er, Hbuf, b1, Ybuf, N);
    // layer 2
    gemm_kernel<64><<<gt, 256, 0, stream>>>(Ybuf, W2, al2, ar2, Hbuf, el, er, N);
    edge_kernel<<<ge, 256, 0, stream>>>(row_ptr, ssrc, el, er, Hbuf, b2, Ybuf, N);
    // layer 3
    gemm_kernel<64><<<gt, 256, 0, stream>>>(Ybuf, W3, al3, ar3, Hbuf, el, er, N);
    edge_kernel<<<ge, 256, 0, stream>>>(row_ptr, ssrc, el, er, Hbuf, b3, (float*)d_out, N);
}

// Round 6
// 393.410 us; speedup vs baseline: 4.2850x; 1.1432x over previous
//
#include <hip/hip_runtime.h>
#include <math.h>

#define HF 64
#define LEAKY 0.2f
#define SCAN_BLOCKS 256
#define SCAN_THREADS 256

// ---------------- CSR build ----------------
// hist also records each edge's rank among same-dst edges -> scatter needs no atomic.

__global__ void hist_kernel(const int* __restrict__ dst, int* __restrict__ cnt,
                            int* __restrict__ rank, int E) {
    int i = blockIdx.x * blockDim.x + threadIdx.x;
    int stride = gridDim.x * blockDim.x;
    for (; i < E; i += stride) rank[i] = atomicAdd(&cnt[dst[i]], 1);
}

// phase 1: per-block chunk sums
__global__ __launch_bounds__(SCAN_THREADS)
void scan_partial(const int* __restrict__ cnt, int* __restrict__ bsum, int n) {
    int chunk = (n + SCAN_BLOCKS - 1) / SCAN_BLOCKS;
    int b0 = blockIdx.x * chunk, b1 = min(b0 + chunk, n);
    int s = 0;
    for (int i = b0 + threadIdx.x; i < b1; i += SCAN_THREADS) s += cnt[i];
#pragma unroll
    for (int off = 32; off; off >>= 1) s += __shfl_xor(s, off);
    __shared__ int wsum[4];
    int wave = threadIdx.x >> 6, lane = threadIdx.x & 63;
    if (lane == 0) wsum[wave] = s;
    __syncthreads();
    if (threadIdx.x == 0) bsum[blockIdx.x] = wsum[0] + wsum[1] + wsum[2] + wsum[3];
}

// phase 2: exclusive scan of the 256 block sums
__global__ __launch_bounds__(SCAN_BLOCKS)
void scan_bsums(const int* __restrict__ bsum, int* __restrict__ boff, int* __restrict__ total) {
    __shared__ int tmp[SCAN_BLOCKS];
    int t = threadIdx.x;
    int v = bsum[t];
    tmp[t] = v;
    __syncthreads();
    for (int off = 1; off < SCAN_BLOCKS; off <<= 1) {
        int u = (t >= off) ? tmp[t - off] : 0;
        __syncthreads();
        tmp[t] += u;
        __syncthreads();
    }
    boff[t] = tmp[t] - v;
    if (t == SCAN_BLOCKS - 1) total[0] = tmp[t];
}

// phase 3: per-chunk exclusive scan with block offset -> row_ptr
__global__ __launch_bounds__(SCAN_THREADS)
void scan_final(const int* __restrict__ cnt, const int* __restrict__ boff,
                const int* __restrict__ total, int* __restrict__ row_ptr, int n) {
    int chunk = (n + SCAN_BLOCKS - 1) / SCAN_BLOCKS;
    int b0 = blockIdx.x * chunk, b1 = min(b0 + chunk, n);
    __shared__ int tile[SCAN_THREADS];
    int carry = boff[blockIdx.x];
    for (int base = b0; base < b1; base += SCAN_THREADS) {
        int i = base + threadIdx.x;
        int v = (i < b1) ? cnt[i] : 0;
        tile[threadIdx.x] = v;
        __syncthreads();
        for (int off = 1; off < SCAN_THREADS; off <<= 1) {
            int u = (threadIdx.x >= off) ? tile[threadIdx.x - off] : 0;
            __syncthreads();
            tile[threadIdx.x] += u;
            __syncthreads();
        }
        if (i < b1) row_ptr[i] = carry + tile[threadIdx.x] - v;
        carry += tile[SCAN_THREADS - 1];
        __syncthreads();
    }
    if (blockIdx.x == SCAN_BLOCKS - 1 && threadIdx.x == 0) row_ptr[n] = total[0];
}

// atomic-free scatter: position fully determined by row_ptr + precomputed rank
__global__ void scatter_kernel(const int* __restrict__ src, const int* __restrict__ dst,
                               const int* __restrict__ rank, const int* __restrict__ row_ptr,
                               int* __restrict__ ssrc, int E) {
    int i = blockIdx.x * blockDim.x + threadIdx.x;
    int stride = gridDim.x * blockDim.x;
    for (; i < E; i += stride) {
        ssrc[row_ptr[dst[i]] + rank[i]] = src[i];
    }
}

// ---------------- GEMM: H = X @ W, el = H a_l, er = H a_r ----------------
// 64-row tile, 256 threads, 4x4 register tile. BOTH operands staged in LDS:
//  - Ws: identity [k][c] copy (no transpose!) -> coalesced global read,
//    conflict-free LDS write; compute read Ws[k][tc*4..+3] spans 64 words
//    across 16 tc-lanes -> 2 lanes/bank = free.
//  - Xs: [row][k ^ ((row&7)<<2)] XOR swizzle -> compute read (rows r,r+4,r+8,
//    r+12 per instr) lands 2-way = free; global read fully coalesced.
// Round-5 version read X direct from global (64 B unique/wave-instr, VMEM
// issue-bound) and transposed W in LDS (8-way write conflicts, 4.4M cycles).

template <int K>
__global__ __launch_bounds__(256)
void gemm_kernel(const float* __restrict__ X, const float* __restrict__ W,
                 const float* __restrict__ al, const float* __restrict__ ar,
                 float* __restrict__ H, float* __restrict__ el, float* __restrict__ er,
                 int n) {
    __shared__ float Ws[K * 64];   // [k][c], native layout
    __shared__ float Xs[64 * K];   // [row][k ^ ((row&7)<<2)]
    int tid = threadIdx.x;
    int r0blk = blockIdx.x * 64;
    constexpr int F4 = K / 4;      // float4 per X row

    // stage W: identity float4 copy
    {
        const float4* Wg = (const float4*)W;
        float4* Wl = (float4*)Ws;
#pragma unroll
        for (int i = 0; i < K / 16; ++i)
            Wl[tid + i * 256] = Wg[tid + i * 256];
    }
    // stage X tile: coalesced global, swizzled LDS
    {
        const float* Xg = X + (size_t)r0blk * K;
#pragma unroll
        for (int i = 0; i < K / 16; ++i) {
            int idx = tid + i * 256;
            int row = idx / F4, kk = idx % F4;
            float4 v = make_float4(0.f, 0.f, 0.f, 0.f);
            if (r0blk + row < n) v = *(const float4*)(Xg + (size_t)row * K + kk * 4);
            *(float4*)&Xs[row * K + ((kk * 4) ^ ((row & 7) << 2))] = v;
        }
    }
    __syncthreads();

    int tc = tid & 15, tr = tid >> 4;
    int r0 = r0blk + tr * 4;

    float acc[4][4] = {};  // [row][col]

#pragma unroll 4
    for (int kq = 0; kq < K; kq += 4) {
        float4 xv[4];
#pragma unroll
        for (int r = 0; r < 4; ++r) {
            int row = tr * 4 + r;
            xv[r] = *(const float4*)&Xs[row * K + (kq ^ ((row & 7) << 2))];
        }
#pragma unroll
        for (int kk = 0; kk < 4; ++kk) {
            float4 wv = *(const float4*)&Ws[(kq + kk) * 64 + tc * 4];
#pragma unroll
            for (int r = 0; r < 4; ++r) {
                float x = kk == 0 ? xv[r].x : kk == 1 ? xv[r].y : kk == 2 ? xv[r].z : xv[r].w;
                acc[r][0] = fmaf(x, wv.x, acc[r][0]);
                acc[r][1] = fmaf(x, wv.y, acc[r][1]);
                acc[r][2] = fmaf(x, wv.z, acc[r][2]);
                acc[r][3] = fmaf(x, wv.w, acc[r][3]);
            }
        }
    }

    // epilogue: store H rows, fused el/er
    float alv[4], arv[4];
#pragma unroll
    for (int i = 0; i < 4; ++i) { alv[i] = al[tc * 4 + i]; arv[i] = ar[tc * 4 + i]; }

#pragma unroll
    for (int r = 0; r < 4; ++r) {
        if (r0 + r >= n) continue;
        *(float4*)(H + (size_t)(r0 + r) * HF + tc * 4) =
            make_float4(acc[r][0], acc[r][1], acc[r][2], acc[r][3]);
        float pl = acc[r][0] * alv[0] + acc[r][1] * alv[1] + acc[r][2] * alv[2] + acc[r][3] * alv[3];
        float pr = acc[r][0] * arv[0] + acc[r][1] * arv[1] + acc[r][2] * arv[2] + acc[r][3] * arv[3];
#pragma unroll
        for (int off = 1; off < 16; off <<= 1) {
            pl += __shfl_xor(pl, off);
            pr += __shfl_xor(pr, off);
        }
        if (tc == 0) { el[r0 + r] = pl; er[r0 + r] = pr; }
    }
}

// ---------------- Edge phase: softmax over incoming edges + aggregation ----------------
// Wave = 4 groups x 16 lanes. Group g handles edge j = 4t+g, loading H rows as
// float4 (16 lanes x 16B = full 256B row). Cross-group merge = 2 float4 shfl_xor.

__global__ __launch_bounds__(256)
void edge_kernel(const int* __restrict__ row_ptr, const int* __restrict__ ssrc,
                 const float* __restrict__ el, const float* __restrict__ er,
                 const float* __restrict__ H, const float* __restrict__ b,
                 float* __restrict__ Y, int n) {
    int wave = threadIdx.x >> 6, lane = threadIdx.x & 63;
    int node = blockIdx.x * 4 + wave;
    if (node >= n) return;
    int g = lane >> 4, fl = lane & 15;
    int s0 = row_ptr[node], s1 = row_ptr[node + 1];
    int d = s1 - s0;
    float ern = er[node];
    const float4* H4 = (const float4*)H;

    if (d <= 64) {
        // one edge per lane in registers
        int sidx = 0;
        float e = -INFINITY;
        if (lane < d) {
            sidx = ssrc[s0 + lane];
            e = el[sidx] + ern;
            e = e > 0.f ? e : LEAKY * e;
        }
        float m = e;
#pragma unroll
        for (int off = 32; off; off >>= 1) m = fmaxf(m, __shfl_xor(m, off));
        float p = (lane < d) ? __expf(e - m) : 0.f;
        float psum = p;
#pragma unroll
        for (int off = 32; off; off >>= 1) psum += __shfl_xor(psum, off);

        float4 acc = make_float4(0.f, 0.f, 0.f, 0.f);
        int nt = (d + 3) >> 2;
        for (int t = 0; t < nt; ++t) {
            int j = t * 4 + g;            // per-lane edge index
            int s = __shfl(sidx, j);      // lanes j>=d give sidx=0 (valid row), p=0
            float pj = __shfl(p, j);
            float4 v = H4[(size_t)s * 16 + fl];
            acc.x = fmaf(pj, v.x, acc.x);
            acc.y = fmaf(pj, v.y, acc.y);
            acc.z = fmaf(pj, v.z, acc.z);
            acc.w = fmaf(pj, v.w, acc.w);
        }
        // merge the 4 groups (lanes ^16, ^32)
#pragma unroll
        for (int off = 16; off <= 32; off <<= 1) {
            acc.x += __shfl_xor(acc.x, off);
            acc.y += __shfl_xor(acc.y, off);
            acc.z += __shfl_xor(acc.z, off);
            acc.w += __shfl_xor(acc.w, off);
        }
        float inv = d ? 1.f / psum : 0.f;
        float4 bv = ((const float4*)b)[fl];
        float4 o;
        o.x = fmaf(acc.x, inv, bv.x);
        o.y = fmaf(acc.y, inv, bv.y);
        o.z = fmaf(acc.z, inv, bv.z);
        o.w = fmaf(acc.w, inv, bv.w);
        o.x = o.x > 0.f ? o.x : 0.f;
        o.y = o.y > 0.f ? o.y : 0.f;
        o.z = o.z > 0.f ? o.z : 0.f;
        o.w = o.w > 0.f ? o.w : 0.f;
        if (g == 0) ((float4*)Y)[(size_t)node * 16 + fl] = o;
    } else {
        // fallback: two-pass, lane = feature
        float m = -INFINITY;
        for (int j = s0 + lane; j < s1; j += 64) {
            float e = el[ssrc[j]] + ern;
            e = e > 0.f ? e : LEAKY * e;
            m = fmaxf(m, e);
        }
#pragma unroll
        for (int off = 32; off; off >>= 1) m = fmaxf(m, __shfl_xor(m, off));
        float acc = 0.f, psum = 0.f;
        for (int j = s0; j < s1; ++j) {
            int s = ssrc[j];
            float e = el[s] + ern;
            e = e > 0.f ? e : LEAKY * e;
            float p = __expf(e - m);
            psum += p;
            acc = fmaf(p, H[(size_t)s * HF + lane], acc);
        }
        float o = acc / psum + b[lane];
        Y[(size_t)node * HF + lane] = o > 0.f ? o : 0.f;
    }
}

// ---------------- launch ----------------

extern "C" void kernel_launch(void* const* d_in, const int* in_sizes, int n_in,
                              void* d_out, int out_size, void* d_ws, size_t ws_size,
                              hipStream_t stream) {
    const int N = in_sizes[0] / 128;
    const int E = in_sizes[1];

    const float* in_feat = (const float*)d_in[0];
    const int* src = (const int*)d_in[1];
    const int* dst = (const int*)d_in[2];
    const float* W1 = (const float*)d_in[3];
    const float* al1 = (const float*)d_in[4];
    const float* ar1 = (const float*)d_in[5];
    const float* b1 = (const float*)d_in[6];
    const float* W2 = (const float*)d_in[7];
    const float* al2 = (const float*)d_in[8];
    const float* ar2 = (const float*)d_in[9];
    const float* b2 = (const float*)d_in[10];
    const float* W3 = (const float*)d_in[11];
    const float* al3 = (const float*)d_in[12];
    const float* ar3 = (const float*)d_in[13];
    const float* b3 = (const float*)d_in[14];

    char* ws = (char*)d_ws;
    size_t off = 0;
    auto alloc = [&](size_t bytes) {
        void* p = ws + off;
        off += (bytes + 255) & ~(size_t)255;
        return p;
    };
    int* cnt = (int*)alloc((size_t)N * 4);
    int* row_ptr = (int*)alloc(((size_t)N + 1) * 4);
    int* rank = (int*)alloc((size_t)E * 4);
    int* ssrc = (int*)alloc((size_t)E * 4);
    float* el = (float*)alloc((size_t)N * 4);
    float* er = (float*)alloc((size_t)N * 4);
    float* Hbuf = (float*)alloc((size_t)N * HF * 4);
    float* Ybuf = (float*)alloc((size_t)N * HF * 4);
    int* bsum = (int*)alloc(SCAN_BLOCKS * 4);
    int* boff = (int*)alloc(SCAN_BLOCKS * 4);
    int* total = (int*)alloc(4);

    hipMemsetAsync(cnt, 0, (size_t)N * 4, stream);
    hist_kernel<<<2048, 256, 0, stream>>>(dst, cnt, rank, E);
    scan_partial<<<SCAN_BLOCKS, SCAN_THREADS, 0, stream>>>(cnt, bsum, N);
    scan_bsums<<<1, SCAN_BLOCKS, 0, stream>>>(bsum, boff, total);
    scan_final<<<SCAN_BLOCKS, SCAN_THREADS, 0, stream>>>(cnt, boff, total, row_ptr, N);
    scatter_kernel<<<2048, 256, 0, stream>>>(src, dst, rank, row_ptr, ssrc, E);

    int gt = (N + 63) / 64;   // gemm tiles
    int ge = (N + 3) / 4;     // edge blocks (4 nodes/block)

    // layer 1
    gemm_kernel<128><<<gt, 256, 0, stream>>>(in_feat, W1, al1, ar1, Hbuf, el, er, N);
    edge_kernel<<<ge, 256, 0, stream>>>(row_ptr, ssrc, el, er, Hbuf, b1, Ybuf, N);
    // layer 2
    gemm_kernel<64><<<gt, 256, 0, stream>>>(Ybuf, W2, al2, ar2, Hbuf, el, er, N);
    edge_kernel<<<ge, 256, 0, stream>>>(row_ptr, ssrc, el, er, Hbuf, b2, Ybuf, N);
    // layer 3
    gemm_kernel<64><<<gt, 256, 0, stream>>>(Ybuf, W3, al3, ar3, Hbuf, el, er, N);
    edge_kernel<<<ge, 256, 0, stream>>>(row_ptr, ssrc, el, er, Hbuf, b3, (float*)d_out, N);
}

// Round 7
// 387.614 us; speedup vs baseline: 4.3490x; 1.0150x over previous
//
#include <hip/hip_runtime.h>
#include <math.h>

#define HF 64
#define LEAKY 0.2f
#define SCAN_BLOCKS 256
#define SCAN_THREADS 256

// ---------------- CSR build ----------------
// hist also records each edge's rank among same-dst edges -> scatter needs no atomic.

__global__ void hist_kernel(const int* __restrict__ dst, int* __restrict__ cnt,
                            int* __restrict__ rank, int E) {
    int i = blockIdx.x * blockDim.x + threadIdx.x;
    int stride = gridDim.x * blockDim.x;
    for (; i < E; i += stride) rank[i] = atomicAdd(&cnt[dst[i]], 1);
}

// phase 1: per-block chunk sums
__global__ __launch_bounds__(SCAN_THREADS)
void scan_partial(const int* __restrict__ cnt, int* __restrict__ bsum, int n) {
    int chunk = (n + SCAN_BLOCKS - 1) / SCAN_BLOCKS;
    int b0 = blockIdx.x * chunk, b1 = min(b0 + chunk, n);
    int s = 0;
    for (int i = b0 + threadIdx.x; i < b1; i += SCAN_THREADS) s += cnt[i];
#pragma unroll
    for (int off = 32; off; off >>= 1) s += __shfl_xor(s, off);
    __shared__ int wsum[4];
    int wave = threadIdx.x >> 6, lane = threadIdx.x & 63;
    if (lane == 0) wsum[wave] = s;
    __syncthreads();
    if (threadIdx.x == 0) bsum[blockIdx.x] = wsum[0] + wsum[1] + wsum[2] + wsum[3];
}

// phase 2: exclusive scan of the 256 block sums
__global__ __launch_bounds__(SCAN_BLOCKS)
void scan_bsums(const int* __restrict__ bsum, int* __restrict__ boff, int* __restrict__ total) {
    __shared__ int tmp[SCAN_BLOCKS];
    int t = threadIdx.x;
    int v = bsum[t];
    tmp[t] = v;
    __syncthreads();
    for (int off = 1; off < SCAN_BLOCKS; off <<= 1) {
        int u = (t >= off) ? tmp[t - off] : 0;
        __syncthreads();
        tmp[t] += u;
        __syncthreads();
    }
    boff[t] = tmp[t] - v;
    if (t == SCAN_BLOCKS - 1) total[0] = tmp[t];
}

// phase 3: per-chunk exclusive scan with block offset -> row_ptr
__global__ __launch_bounds__(SCAN_THREADS)
void scan_final(const int* __restrict__ cnt, const int* __restrict__ boff,
                const int* __restrict__ total, int* __restrict__ row_ptr, int n) {
    int chunk = (n + SCAN_BLOCKS - 1) / SCAN_BLOCKS;
    int b0 = blockIdx.x * chunk, b1 = min(b0 + chunk, n);
    __shared__ int tile[SCAN_THREADS];
    int carry = boff[blockIdx.x];
    for (int base = b0; base < b1; base += SCAN_THREADS) {
        int i = base + threadIdx.x;
        int v = (i < b1) ? cnt[i] : 0;
        tile[threadIdx.x] = v;
        __syncthreads();
        for (int off = 1; off < SCAN_THREADS; off <<= 1) {
            int u = (threadIdx.x >= off) ? tile[threadIdx.x - off] : 0;
            __syncthreads();
            tile[threadIdx.x] += u;
            __syncthreads();
        }
        if (i < b1) row_ptr[i] = carry + tile[threadIdx.x] - v;
        carry += tile[SCAN_THREADS - 1];
        __syncthreads();
    }
    if (blockIdx.x == SCAN_BLOCKS - 1 && threadIdx.x == 0) row_ptr[n] = total[0];
}

// atomic-free scatter: position fully determined by row_ptr + precomputed rank
__global__ void scatter_kernel(const int* __restrict__ src, const int* __restrict__ dst,
                               const int* __restrict__ rank, const int* __restrict__ row_ptr,
                               int* __restrict__ ssrc, int E) {
    int i = blockIdx.x * blockDim.x + threadIdx.x;
    int stride = gridDim.x * blockDim.x;
    for (; i < E; i += stride) {
        ssrc[row_ptr[dst[i]] + rank[i]] = src[i];
    }
}

// ---------------- GEMM: H = X @ W, el = H a_l, er = H a_r ----------------
// 64-row tile, 256 threads, 4x4 register tile. BOTH operands staged in LDS:
//  - Ws: identity [k][c] copy (no transpose) -> conflict-free both sides.
//  - Xs: [row][k ^ ((row&7)<<2)] XOR swizzle -> 2-way reads = free.

template <int K>
__global__ __launch_bounds__(256)
void gemm_kernel(const float* __restrict__ X, const float* __restrict__ W,
                 const float* __restrict__ al, const float* __restrict__ ar,
                 float* __restrict__ H, float* __restrict__ el, float* __restrict__ er,
                 int n) {
    __shared__ float Ws[K * 64];   // [k][c], native layout
    __shared__ float Xs[64 * K];   // [row][k ^ ((row&7)<<2)]
    int tid = threadIdx.x;
    int r0blk = blockIdx.x * 64;
    constexpr int F4 = K / 4;      // float4 per X row

    {
        const float4* Wg = (const float4*)W;
        float4* Wl = (float4*)Ws;
#pragma unroll
        for (int i = 0; i < K / 16; ++i)
            Wl[tid + i * 256] = Wg[tid + i * 256];
    }
    {
        const float* Xg = X + (size_t)r0blk * K;
#pragma unroll
        for (int i = 0; i < K / 16; ++i) {
            int idx = tid + i * 256;
            int row = idx / F4, kk = idx % F4;
            float4 v = make_float4(0.f, 0.f, 0.f, 0.f);
            if (r0blk + row < n) v = *(const float4*)(Xg + (size_t)row * K + kk * 4);
            *(float4*)&Xs[row * K + ((kk * 4) ^ ((row & 7) << 2))] = v;
        }
    }
    __syncthreads();

    int tc = tid & 15, tr = tid >> 4;
    int r0 = r0blk + tr * 4;

    float acc[4][4] = {};  // [row][col]

#pragma unroll 4
    for (int kq = 0; kq < K; kq += 4) {
        float4 xv[4];
#pragma unroll
        for (int r = 0; r < 4; ++r) {
            int row = tr * 4 + r;
            xv[r] = *(const float4*)&Xs[row * K + (kq ^ ((row & 7) << 2))];
        }
#pragma unroll
        for (int kk = 0; kk < 4; ++kk) {
            float4 wv = *(const float4*)&Ws[(kq + kk) * 64 + tc * 4];
#pragma unroll
            for (int r = 0; r < 4; ++r) {
                float x = kk == 0 ? xv[r].x : kk == 1 ? xv[r].y : kk == 2 ? xv[r].z : xv[r].w;
                acc[r][0] = fmaf(x, wv.x, acc[r][0]);
                acc[r][1] = fmaf(x, wv.y, acc[r][1]);
                acc[r][2] = fmaf(x, wv.z, acc[r][2]);
                acc[r][3] = fmaf(x, wv.w, acc[r][3]);
            }
        }
    }

    float alv[4], arv[4];
#pragma unroll
    for (int i = 0; i < 4; ++i) { alv[i] = al[tc * 4 + i]; arv[i] = ar[tc * 4 + i]; }

#pragma unroll
    for (int r = 0; r < 4; ++r) {
        if (r0 + r >= n) continue;
        *(float4*)(H + (size_t)(r0 + r) * HF + tc * 4) =
            make_float4(acc[r][0], acc[r][1], acc[r][2], acc[r][3]);
        float pl = acc[r][0] * alv[0] + acc[r][1] * alv[1] + acc[r][2] * alv[2] + acc[r][3] * alv[3];
        float pr = acc[r][0] * arv[0] + acc[r][1] * arv[1] + acc[r][2] * arv[2] + acc[r][3] * arv[3];
#pragma unroll
        for (int off = 1; off < 16; off <<= 1) {
            pl += __shfl_xor(pl, off);
            pr += __shfl_xor(pr, off);
        }
        if (tc == 0) { el[r0 + r] = pl; er[r0 + r] = pr; }
    }
}

// ---------------- Edge phase: softmax over incoming edges + aggregation ----------------
// Wave = 4 groups x 16 lanes. Aggregation processes 16 edges per chunk (4 per
// group): 8 shfl broadcasts, then 4 INDEPENDENT float4 gathers issued
// back-to-back (first FMA waits at vmcnt(3) -> 4 loads in flight), then FMAs.
// Round-6 version interleaved shfl/gather/fma per edge -> fma stalled the next
// gather -> 1 load in flight -> latency-bound at 35% VALU.

__global__ __launch_bounds__(256)
void edge_kernel(const int* __restrict__ row_ptr, const int* __restrict__ ssrc,
                 const float* __restrict__ el, const float* __restrict__ er,
                 const float* __restrict__ H, const float* __restrict__ b,
                 float* __restrict__ Y, int n) {
    int wave = threadIdx.x >> 6, lane = threadIdx.x & 63;
    int node = blockIdx.x * 4 + wave;
    if (node >= n) return;
    int g = lane >> 4, fl = lane & 15;
    int s0 = row_ptr[node], s1 = row_ptr[node + 1];
    int d = s1 - s0;
    float ern = er[node];
    const float4* H4 = (const float4*)H;

    if (d <= 64) {
        // one edge per lane in registers
        int sidx = 0;
        float e = -INFINITY;
        if (lane < d) {
            sidx = ssrc[s0 + lane];
            e = el[sidx] + ern;
            e = e > 0.f ? e : LEAKY * e;
        }
        float m = e;
#pragma unroll
        for (int off = 32; off; off >>= 1) m = fmaxf(m, __shfl_xor(m, off));
        float p = (lane < d) ? __expf(e - m) : 0.f;
        float psum = p;
#pragma unroll
        for (int off = 32; off; off >>= 1) psum += __shfl_xor(psum, off);

        float4 acc = make_float4(0.f, 0.f, 0.f, 0.f);
        int nchunk = (d + 15) >> 4;
        for (int c = 0; c < nchunk; ++c) {
            int jb = c * 16 + g;                 // this group's 4 edges: jb, jb+4, jb+8, jb+12
            int s0_ = __shfl(sidx, jb);          // lanes >= d hold sidx=0, p=0 -> harmless
            int s1_ = __shfl(sidx, jb + 4);
            int s2_ = __shfl(sidx, jb + 8);
            int s3_ = __shfl(sidx, jb + 12);
            float p0 = __shfl(p, jb);
            float p1 = __shfl(p, jb + 4);
            float p2 = __shfl(p, jb + 8);
            float p3 = __shfl(p, jb + 12);
            float4 v0 = H4[(size_t)s0_ * 16 + fl];
            float4 v1 = H4[(size_t)s1_ * 16 + fl];
            float4 v2 = H4[(size_t)s2_ * 16 + fl];
            float4 v3 = H4[(size_t)s3_ * 16 + fl];
            acc.x = fmaf(p0, v0.x, acc.x);
            acc.y = fmaf(p0, v0.y, acc.y);
            acc.z = fmaf(p0, v0.z, acc.z);
            acc.w = fmaf(p0, v0.w, acc.w);
            acc.x = fmaf(p1, v1.x, acc.x);
            acc.y = fmaf(p1, v1.y, acc.y);
            acc.z = fmaf(p1, v1.z, acc.z);
            acc.w = fmaf(p1, v1.w, acc.w);
            acc.x = fmaf(p2, v2.x, acc.x);
            acc.y = fmaf(p2, v2.y, acc.y);
            acc.z = fmaf(p2, v2.z, acc.z);
            acc.w = fmaf(p2, v2.w, acc.w);
            acc.x = fmaf(p3, v3.x, acc.x);
            acc.y = fmaf(p3, v3.y, acc.y);
            acc.z = fmaf(p3, v3.z, acc.z);
            acc.w = fmaf(p3, v3.w, acc.w);
        }
        // merge the 4 groups (lanes ^16, ^32)
#pragma unroll
        for (int off = 16; off <= 32; off <<= 1) {
            acc.x += __shfl_xor(acc.x, off);
            acc.y += __shfl_xor(acc.y, off);
            acc.z += __shfl_xor(acc.z, off);
            acc.w += __shfl_xor(acc.w, off);
        }
        float inv = d ? 1.f / psum : 0.f;
        float4 bv = ((const float4*)b)[fl];
        float4 o;
        o.x = fmaf(acc.x, inv, bv.x);
        o.y = fmaf(acc.y, inv, bv.y);
        o.z = fmaf(acc.z, inv, bv.z);
        o.w = fmaf(acc.w, inv, bv.w);
        o.x = o.x > 0.f ? o.x : 0.f;
        o.y = o.y > 0.f ? o.y : 0.f;
        o.z = o.z > 0.f ? o.z : 0.f;
        o.w = o.w > 0.f ? o.w : 0.f;
        if (g == 0) ((float4*)Y)[(size_t)node * 16 + fl] = o;
    } else {
        // fallback: two-pass, lane = feature
        float m = -INFINITY;
        for (int j = s0 + lane; j < s1; j += 64) {
            float e = el[ssrc[j]] + ern;
            e = e > 0.f ? e : LEAKY * e;
            m = fmaxf(m, e);
        }
#pragma unroll
        for (int off = 32; off; off >>= 1) m = fmaxf(m, __shfl_xor(m, off));
        float acc = 0.f, psum = 0.f;
        for (int j = s0; j < s1; ++j) {
            int s = ssrc[j];
            float e = el[s] + ern;
            e = e > 0.f ? e : LEAKY * e;
            float p = __expf(e - m);
            psum += p;
            acc = fmaf(p, H[(size_t)s * HF + lane], acc);
        }
        float o = acc / psum + b[lane];
        Y[(size_t)node * HF + lane] = o > 0.f ? o : 0.f;
    }
}

// ---------------- launch ----------------

extern "C" void kernel_launch(void* const* d_in, const int* in_sizes, int n_in,
                              void* d_out, int out_size, void* d_ws, size_t ws_size,
                              hipStream_t stream) {
    const int N = in_sizes[0] / 128;
    const int E = in_sizes[1];

    const float* in_feat = (const float*)d_in[0];
    const int* src = (const int*)d_in[1];
    const int* dst = (const int*)d_in[2];
    const float* W1 = (const float*)d_in[3];
    const float* al1 = (const float*)d_in[4];
    const float* ar1 = (const float*)d_in[5];
    const float* b1 = (const float*)d_in[6];
    const float* W2 = (const float*)d_in[7];
    const float* al2 = (const float*)d_in[8];
    const float* ar2 = (const float*)d_in[9];
    const float* b2 = (const float*)d_in[10];
    const float* W3 = (const float*)d_in[11];
    const float* al3 = (const float*)d_in[12];
    const float* ar3 = (const float*)d_in[13];
    const float* b3 = (const float*)d_in[14];

    char* ws = (char*)d_ws;
    size_t off = 0;
    auto alloc = [&](size_t bytes) {
        void* p = ws + off;
        off += (bytes + 255) & ~(size_t)255;
        return p;
    };
    int* cnt = (int*)alloc((size_t)N * 4);
    int* row_ptr = (int*)alloc(((size_t)N + 1) * 4);
    int* rank = (int*)alloc((size_t)E * 4);
    int* ssrc = (int*)alloc((size_t)E * 4);
    float* el = (float*)alloc((size_t)N * 4);
    float* er = (float*)alloc((size_t)N * 4);
    float* Hbuf = (float*)alloc((size_t)N * HF * 4);
    float* Ybuf = (float*)alloc((size_t)N * HF * 4);
    int* bsum = (int*)alloc(SCAN_BLOCKS * 4);
    int* boff = (int*)alloc(SCAN_BLOCKS * 4);
    int* total = (int*)alloc(4);

    hipMemsetAsync(cnt, 0, (size_t)N * 4, stream);
    hist_kernel<<<2048, 256, 0, stream>>>(dst, cnt, rank, E);
    scan_partial<<<SCAN_BLOCKS, SCAN_THREADS, 0, stream>>>(cnt, bsum, N);
    scan_bsums<<<1, SCAN_BLOCKS, 0, stream>>>(bsum, boff, total);
    scan_final<<<SCAN_BLOCKS, SCAN_THREADS, 0, stream>>>(cnt, boff, total, row_ptr, N);
    scatter_kernel<<<2048, 256, 0, stream>>>(src, dst, rank, row_ptr, ssrc, E);

    int gt = (N + 63) / 64;   // gemm tiles
    int ge = (N + 3) / 4;     // edge blocks (4 nodes/block)

    // layer 1
    gemm_kernel<128><<<gt, 256, 0, stream>>>(in_feat, W1, al1, ar1, Hbuf, el, er, N);
    edge_kernel<<<ge, 256, 0, stream>>>(row_ptr, ssrc, el, er, Hbuf, b1, Ybuf, N);
    // layer 2
    gemm_kernel<64><<<gt, 256, 0, stream>>>(Ybuf, W2, al2, ar2, Hbuf, el, er, N);
    edge_kernel<<<ge, 256, 0, stream>>>(row_ptr, ssrc, el, er, Hbuf, b2, Ybuf, N);
    // layer 3
    gemm_kernel<64><<<gt, 256, 0, stream>>>(Ybuf, W3, al3, ar3, Hbuf, el, er, N);
    edge_kernel<<<ge, 256, 0, stream>>>(row_ptr, ssrc, el, er, Hbuf, b3, (float*)d_out, N);
}

// Round 8
// 341.031 us; speedup vs baseline: 4.9431x; 1.1366x over previous
//
#include <hip/hip_runtime.h>
#include <hip/hip_fp16.h>
#include <math.h>

#define HF 64
#define LEAKY 0.2f
#define SCAN_BLOCKS 256
#define SCAN_THREADS 256

// ---------------- CSR build ----------------
// hist also records each edge's rank among same-dst edges -> scatter needs no atomic.

__global__ void hist_kernel(const int* __restrict__ dst, int* __restrict__ cnt,
                            int* __restrict__ rank, int E) {
    int i = blockIdx.x * blockDim.x + threadIdx.x;
    int stride = gridDim.x * blockDim.x;
    for (; i < E; i += stride) rank[i] = atomicAdd(&cnt[dst[i]], 1);
}

// phase 1: per-block chunk sums
__global__ __launch_bounds__(SCAN_THREADS)
void scan_partial(const int* __restrict__ cnt, int* __restrict__ bsum, int n) {
    int chunk = (n + SCAN_BLOCKS - 1) / SCAN_BLOCKS;
    int b0 = blockIdx.x * chunk, b1 = min(b0 + chunk, n);
    int s = 0;
    for (int i = b0 + threadIdx.x; i < b1; i += SCAN_THREADS) s += cnt[i];
#pragma unroll
    for (int off = 32; off; off >>= 1) s += __shfl_xor(s, off);
    __shared__ int wsum[4];
    int wave = threadIdx.x >> 6, lane = threadIdx.x & 63;
    if (lane == 0) wsum[wave] = s;
    __syncthreads();
    if (threadIdx.x == 0) bsum[blockIdx.x] = wsum[0] + wsum[1] + wsum[2] + wsum[3];
}

// phase 2: exclusive scan of the 256 block sums
__global__ __launch_bounds__(SCAN_BLOCKS)
void scan_bsums(const int* __restrict__ bsum, int* __restrict__ boff, int* __restrict__ total) {
    __shared__ int tmp[SCAN_BLOCKS];
    int t = threadIdx.x;
    int v = bsum[t];
    tmp[t] = v;
    __syncthreads();
    for (int off = 1; off < SCAN_BLOCKS; off <<= 1) {
        int u = (t >= off) ? tmp[t - off] : 0;
        __syncthreads();
        tmp[t] += u;
        __syncthreads();
    }
    boff[t] = tmp[t] - v;
    if (t == SCAN_BLOCKS - 1) total[0] = tmp[t];
}

// phase 3: per-chunk exclusive scan with block offset -> row_ptr
__global__ __launch_bounds__(SCAN_THREADS)
void scan_final(const int* __restrict__ cnt, const int* __restrict__ boff,
                const int* __restrict__ total, int* __restrict__ row_ptr, int n) {
    int chunk = (n + SCAN_BLOCKS - 1) / SCAN_BLOCKS;
    int b0 = blockIdx.x * chunk, b1 = min(b0 + chunk, n);
    __shared__ int tile[SCAN_THREADS];
    int carry = boff[blockIdx.x];
    for (int base = b0; base < b1; base += SCAN_THREADS) {
        int i = base + threadIdx.x;
        int v = (i < b1) ? cnt[i] : 0;
        tile[threadIdx.x] = v;
        __syncthreads();
        for (int off = 1; off < SCAN_THREADS; off <<= 1) {
            int u = (threadIdx.x >= off) ? tile[threadIdx.x - off] : 0;
            __syncthreads();
            tile[threadIdx.x] += u;
            __syncthreads();
        }
        if (i < b1) row_ptr[i] = carry + tile[threadIdx.x] - v;
        carry += tile[SCAN_THREADS - 1];
        __syncthreads();
    }
    if (blockIdx.x == SCAN_BLOCKS - 1 && threadIdx.x == 0) row_ptr[n] = total[0];
}

// atomic-free scatter: position fully determined by row_ptr + precomputed rank
__global__ void scatter_kernel(const int* __restrict__ src, const int* __restrict__ dst,
                               const int* __restrict__ rank, const int* __restrict__ row_ptr,
                               int* __restrict__ ssrc, int E) {
    int i = blockIdx.x * blockDim.x + threadIdx.x;
    int stride = gridDim.x * blockDim.x;
    for (; i < E; i += stride) {
        ssrc[row_ptr[dst[i]] + rank[i]] = src[i];
    }
}

// ---------------- GEMM: H2(fp16) = X @ W, el = H a_l, er = H a_r ----------------
// 64-row tile, 256 threads, 4x4 register tile, both operands in LDS.
// H is consumed ONLY by the edge gather -> store it as fp16 (halves the random
// gather line traffic: 256B row -> 128B row = 4 lines -> 2). el/er computed
// from the f32 accumulators, so softmax precision is unchanged.

template <int K>
__global__ __launch_bounds__(256)
void gemm_kernel(const float* __restrict__ X, const float* __restrict__ W,
                 const float* __restrict__ al, const float* __restrict__ ar,
                 __half* __restrict__ H2, float* __restrict__ el, float* __restrict__ er,
                 int n) {
    __shared__ float Ws[K * 64];   // [k][c], native layout
    __shared__ float Xs[64 * K];   // [row][k ^ ((row&7)<<2)]
    int tid = threadIdx.x;
    int r0blk = blockIdx.x * 64;
    constexpr int F4 = K / 4;      // float4 per X row

    {
        const float4* Wg = (const float4*)W;
        float4* Wl = (float4*)Ws;
#pragma unroll
        for (int i = 0; i < K / 16; ++i)
            Wl[tid + i * 256] = Wg[tid + i * 256];
    }
    {
        const float* Xg = X + (size_t)r0blk * K;
#pragma unroll
        for (int i = 0; i < K / 16; ++i) {
            int idx = tid + i * 256;
            int row = idx / F4, kk = idx % F4;
            float4 v = make_float4(0.f, 0.f, 0.f, 0.f);
            if (r0blk + row < n) v = *(const float4*)(Xg + (size_t)row * K + kk * 4);
            *(float4*)&Xs[row * K + ((kk * 4) ^ ((row & 7) << 2))] = v;
        }
    }
    __syncthreads();

    int tc = tid & 15, tr = tid >> 4;
    int r0 = r0blk + tr * 4;

    float acc[4][4] = {};  // [row][col]

#pragma unroll 4
    for (int kq = 0; kq < K; kq += 4) {
        float4 xv[4];
#pragma unroll
        for (int r = 0; r < 4; ++r) {
            int row = tr * 4 + r;
            xv[r] = *(const float4*)&Xs[row * K + (kq ^ ((row & 7) << 2))];
        }
#pragma unroll
        for (int kk = 0; kk < 4; ++kk) {
            float4 wv = *(const float4*)&Ws[(kq + kk) * 64 + tc * 4];
#pragma unroll
            for (int r = 0; r < 4; ++r) {
                float x = kk == 0 ? xv[r].x : kk == 1 ? xv[r].y : kk == 2 ? xv[r].z : xv[r].w;
                acc[r][0] = fmaf(x, wv.x, acc[r][0]);
                acc[r][1] = fmaf(x, wv.y, acc[r][1]);
                acc[r][2] = fmaf(x, wv.z, acc[r][2]);
                acc[r][3] = fmaf(x, wv.w, acc[r][3]);
            }
        }
    }

    float alv[4], arv[4];
#pragma unroll
    for (int i = 0; i < 4; ++i) { alv[i] = al[tc * 4 + i]; arv[i] = ar[tc * 4 + i]; }

#pragma unroll
    for (int r = 0; r < 4; ++r) {
        if (r0 + r >= n) continue;
        __half2 h01 = __floats2half2_rn(acc[r][0], acc[r][1]);
        __half2 h23 = __floats2half2_rn(acc[r][2], acc[r][3]);
        uint2 u = make_uint2(*(unsigned*)&h01, *(unsigned*)&h23);
        ((uint2*)(H2 + (size_t)(r0 + r) * HF))[tc] = u;
        float pl = acc[r][0] * alv[0] + acc[r][1] * alv[1] + acc[r][2] * alv[2] + acc[r][3] * alv[3];
        float pr = acc[r][0] * arv[0] + acc[r][1] * arv[1] + acc[r][2] * arv[2] + acc[r][3] * arv[3];
#pragma unroll
        for (int off = 1; off < 16; off <<= 1) {
            pl += __shfl_xor(pl, off);
            pr += __shfl_xor(pr, off);
        }
        if (tc == 0) { el[r0 + r] = pl; er[r0 + r] = pr; }
    }
}

// ---------------- Edge phase: softmax over incoming edges + aggregation ----------------
// Wave = 4 groups x 16 lanes; H rows are fp16 (128B, 16 lanes x uint2).
// Aggregation: 32 edges/chunk (8 per group), 8 independent 8B gathers in
// flight, then cvt+FMA. Lanes past d broadcast (s=0, p=0) -> hot row-0 line.

__global__ __launch_bounds__(256)
void edge_kernel(const int* __restrict__ row_ptr, const int* __restrict__ ssrc,
                 const float* __restrict__ el, const float* __restrict__ er,
                 const __half* __restrict__ H2, const float* __restrict__ b,
                 float* __restrict__ Y, int n) {
    int wave = threadIdx.x >> 6, lane = threadIdx.x & 63;
    int node = blockIdx.x * 4 + wave;
    if (node >= n) return;
    int g = lane >> 4, fl = lane & 15;
    int s0 = row_ptr[node], s1 = row_ptr[node + 1];
    int d = s1 - s0;
    float ern = er[node];
    const uint2* H2v = (const uint2*)H2;

    if (d <= 64) {
        // one edge per lane in registers
        int sidx = 0;
        float e = -INFINITY;
        if (lane < d) {
            sidx = ssrc[s0 + lane];
            e = el[sidx] + ern;
            e = e > 0.f ? e : LEAKY * e;
        }
        float m = e;
#pragma unroll
        for (int off = 32; off; off >>= 1) m = fmaxf(m, __shfl_xor(m, off));
        float p = (lane < d) ? __expf(e - m) : 0.f;
        float psum = p;
#pragma unroll
        for (int off = 32; off; off >>= 1) psum += __shfl_xor(psum, off);

        float4 acc = make_float4(0.f, 0.f, 0.f, 0.f);
        int nchunk = (d + 31) >> 5;
        for (int c = 0; c < nchunk; ++c) {
            int jb = c * 32 + g;   // this group's 8 edges: jb + 4u, u = 0..7
            int ss[8];
            float pp[8];
#pragma unroll
            for (int u = 0; u < 8; ++u) {
                ss[u] = __shfl(sidx, jb + 4 * u);
                pp[u] = __shfl(p, jb + 4 * u);
            }
            uint2 vv[8];
#pragma unroll
            for (int u = 0; u < 8; ++u) vv[u] = H2v[(size_t)ss[u] * 16 + fl];
#pragma unroll
            for (int u = 0; u < 8; ++u) {
                __half2 a = *(__half2*)&vv[u].x;
                __half2 b2 = *(__half2*)&vv[u].y;
                float2 fa = __half22float2(a);
                float2 fb = __half22float2(b2);
                acc.x = fmaf(pp[u], fa.x, acc.x);
                acc.y = fmaf(pp[u], fa.y, acc.y);
                acc.z = fmaf(pp[u], fb.x, acc.z);
                acc.w = fmaf(pp[u], fb.y, acc.w);
            }
        }
        // merge the 4 groups (lanes ^16, ^32)
#pragma unroll
        for (int off = 16; off <= 32; off <<= 1) {
            acc.x += __shfl_xor(acc.x, off);
            acc.y += __shfl_xor(acc.y, off);
            acc.z += __shfl_xor(acc.z, off);
            acc.w += __shfl_xor(acc.w, off);
        }
        float inv = d ? 1.f / psum : 0.f;
        float4 bv = ((const float4*)b)[fl];
        float4 o;
        o.x = fmaf(acc.x, inv, bv.x);
        o.y = fmaf(acc.y, inv, bv.y);
        o.z = fmaf(acc.z, inv, bv.z);
        o.w = fmaf(acc.w, inv, bv.w);
        o.x = o.x > 0.f ? o.x : 0.f;
        o.y = o.y > 0.f ? o.y : 0.f;
        o.z = o.z > 0.f ? o.z : 0.f;
        o.w = o.w > 0.f ? o.w : 0.f;
        if (g == 0) ((float4*)Y)[(size_t)node * 16 + fl] = o;
    } else {
        // fallback: two-pass, lane = feature
        float m = -INFINITY;
        for (int j = s0 + lane; j < s1; j += 64) {
            float e = el[ssrc[j]] + ern;
            e = e > 0.f ? e : LEAKY * e;
            m = fmaxf(m, e);
        }
#pragma unroll
        for (int off = 32; off; off >>= 1) m = fmaxf(m, __shfl_xor(m, off));
        float acc = 0.f, psum = 0.f;
        for (int j = s0; j < s1; ++j) {
            int s = ssrc[j];
            float e = el[s] + ern;
            e = e > 0.f ? e : LEAKY * e;
            float p = __expf(e - m);
            psum += p;
            acc = fmaf(p, __half2float(H2[(size_t)s * HF + lane]), acc);
        }
        float o = acc / psum + b[lane];
        Y[(size_t)node * HF + lane] = o > 0.f ? o : 0.f;
    }
}

// ---------------- launch ----------------

extern "C" void kernel_launch(void* const* d_in, const int* in_sizes, int n_in,
                              void* d_out, int out_size, void* d_ws, size_t ws_size,
                              hipStream_t stream) {
    const int N = in_sizes[0] / 128;
    const int E = in_sizes[1];

    const float* in_feat = (const float*)d_in[0];
    const int* src = (const int*)d_in[1];
    const int* dst = (const int*)d_in[2];
    const float* W1 = (const float*)d_in[3];
    const float* al1 = (const float*)d_in[4];
    const float* ar1 = (const float*)d_in[5];
    const float* b1 = (const float*)d_in[6];
    const float* W2 = (const float*)d_in[7];
    const float* al2 = (const float*)d_in[8];
    const float* ar2 = (const float*)d_in[9];
    const float* b2 = (const float*)d_in[10];
    const float* W3 = (const float*)d_in[11];
    const float* al3 = (const float*)d_in[12];
    const float* ar3 = (const float*)d_in[13];
    const float* b3 = (const float*)d_in[14];

    char* ws = (char*)d_ws;
    size_t off = 0;
    auto alloc = [&](size_t bytes) {
        void* p = ws + off;
        off += (bytes + 255) & ~(size_t)255;
        return p;
    };
    int* cnt = (int*)alloc((size_t)N * 4);
    int* row_ptr = (int*)alloc(((size_t)N + 1) * 4);
    int* rank = (int*)alloc((size_t)E * 4);
    int* ssrc = (int*)alloc((size_t)E * 4);
    float* el = (float*)alloc((size_t)N * 4);
    float* er = (float*)alloc((size_t)N * 4);
    __half* H2buf = (__half*)alloc((size_t)N * HF * 2);
    float* Ybuf = (float*)alloc((size_t)N * HF * 4);
    int* bsum = (int*)alloc(SCAN_BLOCKS * 4);
    int* boff = (int*)alloc(SCAN_BLOCKS * 4);
    int* total = (int*)alloc(4);

    hipMemsetAsync(cnt, 0, (size_t)N * 4, stream);
    hist_kernel<<<2048, 256, 0, stream>>>(dst, cnt, rank, E);
    scan_partial<<<SCAN_BLOCKS, SCAN_THREADS, 0, stream>>>(cnt, bsum, N);
    scan_bsums<<<1, SCAN_BLOCKS, 0, stream>>>(bsum, boff, total);
    scan_final<<<SCAN_BLOCKS, SCAN_THREADS, 0, stream>>>(cnt, boff, total, row_ptr, N);
    scatter_kernel<<<2048, 256, 0, stream>>>(src, dst, rank, row_ptr, ssrc, E);

    int gt = (N + 63) / 64;   // gemm tiles
    int ge = (N + 3) / 4;     // edge blocks (4 nodes/block)

    // layer 1
    gemm_kernel<128><<<gt, 256, 0, stream>>>(in_feat, W1, al1, ar1, H2buf, el, er, N);
    edge_kernel<<<ge, 256, 0, stream>>>(row_ptr, ssrc, el, er, H2buf, b1, Ybuf, N);
    // layer 2
    gemm_kernel<64><<<gt, 256, 0, stream>>>(Ybuf, W2, al2, ar2, H2buf, el, er, N);
    edge_kernel<<<ge, 256, 0, stream>>>(row_ptr, ssrc, el, er, H2buf, b2, Ybuf, N);
    // layer 3
    gemm_kernel<64><<<gt, 256, 0, stream>>>(Ybuf, W3, al3, ar3, H2buf, el, er, N);
    edge_kernel<<<ge, 256, 0, stream>>>(row_ptr, ssrc, el, er, H2buf, b3, (float*)d_out, N);
}

// Round 9
// 295.080 us; speedup vs baseline: 5.7128x; 1.1557x over previous
//
#include <hip/hip_runtime.h>
#include <hip/hip_fp16.h>
#include <math.h>

#define HF 64
#define LEAKY 0.2f
#define NBLK 256          // partition blocks
#define NPB 512           // nodes per bucket (bucket = dst >> 9)
#define MAXNB 256         // static LDS sizing for bucket counters

// ---------------- CSR build: two-level bucket partition ----------------
// All atomics in LDS; random global writes confined to L2-resident windows.

// K1: per-(block,bucket) counts
__global__ __launch_bounds__(256)
void part_count(const int* __restrict__ dst, int* __restrict__ Cmat, int E, int nb) {
    __shared__ int lc[MAXNB];
    int tid = threadIdx.x;
    for (int t = tid; t < nb; t += 256) lc[t] = 0;
    __syncthreads();
    int chunk = (E + NBLK - 1) / NBLK;
    int b0 = blockIdx.x * chunk, b1 = min(b0 + chunk, E);
    for (int i = b0 + tid; i < b1; i += 256)
        atomicAdd(&lc[dst[i] >> 9], 1);
    __syncthreads();
    for (int t = tid; t < nb; t += 256) Cmat[t * NBLK + blockIdx.x] = lc[t];
}

// K2: bucket totals -> bbase (exclusive); per-(bucket,block) offsets Omat
__global__ __launch_bounds__(256)
void scan_offsets(const int* __restrict__ Cmat, int* __restrict__ Omat,
                  int* __restrict__ bbase, int E, int nb) {
    __shared__ int tot[256];
    int t = threadIdx.x;
    int s = 0;
    if (t < nb)
        for (int blk = 0; blk < NBLK; ++blk) s += Cmat[t * NBLK + blk];
    tot[t] = s;
    __syncthreads();
    for (int off = 1; off < 256; off <<= 1) {
        int u = (t >= off) ? tot[t - off] : 0;
        __syncthreads();
        tot[t] += u;
        __syncthreads();
    }
    int excl = tot[t] - s;
    if (t < nb) {
        bbase[t] = excl;
        int run = excl;
        for (int blk = 0; blk < NBLK; ++blk) {
            Omat[t * NBLK + blk] = run;
            run += Cmat[t * NBLK + blk];
        }
    }
    if (t == 0) bbase[nb] = E;
}

// K3: partition edges into bucket segments (contiguous per-(block,bucket) runs)
__global__ __launch_bounds__(256)
void part_scatter(const int* __restrict__ src, const int* __restrict__ dst,
                  const int* __restrict__ Omat, int2* __restrict__ part, int E, int nb) {
    __shared__ int ocur[MAXNB];
    int tid = threadIdx.x;
    for (int t = tid; t < nb; t += 256) ocur[t] = Omat[t * NBLK + blockIdx.x];
    __syncthreads();
    int chunk = (E + NBLK - 1) / NBLK;
    int b0 = blockIdx.x * chunk, b1 = min(b0 + chunk, E);
    for (int i = b0 + tid; i < b1; i += 256) {
        int s = src[i], d = dst[i];
        int pos = atomicAdd(&ocur[d >> 9], 1);
        part[pos] = make_int2(s, d);
    }
}

// K4: per-bucket CSR (LDS count + scan + slot-bump scatter)
__global__ __launch_bounds__(NPB)
void bucket_csr(const int2* __restrict__ part, const int* __restrict__ bbase,
                int* __restrict__ row_ptr, int* __restrict__ ssrc, int N, int E, int nb) {
    int b = blockIdx.x, tid = threadIdx.x;
    int bstart = bbase[b], bend = bbase[b + 1];
    int nb0 = b << 9;
    __shared__ int cnt[NPB];
    cnt[tid] = 0;
    __syncthreads();
    for (int i = bstart + tid; i < bend; i += NPB)
        atomicAdd(&cnt[part[i].y & (NPB - 1)], 1);
    __syncthreads();
    int v = cnt[tid];
    // inclusive scan in place
    for (int off = 1; off < NPB; off <<= 1) {
        int u = (tid >= off) ? cnt[tid - off] : 0;
        __syncthreads();
        cnt[tid] += u;
        __syncthreads();
    }
    int excl = cnt[tid] - v;
    int node = nb0 + tid;
    if (node < N) row_ptr[node] = bstart + excl;
    __syncthreads();
    cnt[tid] = bstart + excl;   // running slot cursor (global offset)
    __syncthreads();
    for (int i = bstart + tid; i < bend; i += NPB) {
        int2 e = part[i];
        int slot = atomicAdd(&cnt[e.y & (NPB - 1)], 1);
        ssrc[slot] = e.x;
    }
    if (b == nb - 1 && tid == 0) row_ptr[N] = E;
}

// ---------------- GEMM: H2(fp16) = X @ W, el = H a_l, er = H a_r ----------------
// 64-row tile, 256 threads, 4x4 register tile, both operands in LDS.
// H consumed only by the edge gather -> fp16 (halves random gather line traffic).

template <int K>
__global__ __launch_bounds__(256)
void gemm_kernel(const float* __restrict__ X, const float* __restrict__ W,
                 const float* __restrict__ al, const float* __restrict__ ar,
                 __half* __restrict__ H2, float* __restrict__ el, float* __restrict__ er,
                 int n) {
    __shared__ float Ws[K * 64];   // [k][c], native layout
    __shared__ float Xs[64 * K];   // [row][k ^ ((row&7)<<2)]
    int tid = threadIdx.x;
    int r0blk = blockIdx.x * 64;
    constexpr int F4 = K / 4;

    {
        const float4* Wg = (const float4*)W;
        float4* Wl = (float4*)Ws;
#pragma unroll
        for (int i = 0; i < K / 16; ++i)
            Wl[tid + i * 256] = Wg[tid + i * 256];
    }
    {
        const float* Xg = X + (size_t)r0blk * K;
#pragma unroll
        for (int i = 0; i < K / 16; ++i) {
            int idx = tid + i * 256;
            int row = idx / F4, kk = idx % F4;
            float4 v = make_float4(0.f, 0.f, 0.f, 0.f);
            if (r0blk + row < n) v = *(const float4*)(Xg + (size_t)row * K + kk * 4);
            *(float4*)&Xs[row * K + ((kk * 4) ^ ((row & 7) << 2))] = v;
        }
    }
    __syncthreads();

    int tc = tid & 15, tr = tid >> 4;
    int r0 = r0blk + tr * 4;

    float acc[4][4] = {};

#pragma unroll 4
    for (int kq = 0; kq < K; kq += 4) {
        float4 xv[4];
#pragma unroll
        for (int r = 0; r < 4; ++r) {
            int row = tr * 4 + r;
            xv[r] = *(const float4*)&Xs[row * K + (kq ^ ((row & 7) << 2))];
        }
#pragma unroll
        for (int kk = 0; kk < 4; ++kk) {
            float4 wv = *(const float4*)&Ws[(kq + kk) * 64 + tc * 4];
#pragma unroll
            for (int r = 0; r < 4; ++r) {
                float x = kk == 0 ? xv[r].x : kk == 1 ? xv[r].y : kk == 2 ? xv[r].z : xv[r].w;
                acc[r][0] = fmaf(x, wv.x, acc[r][0]);
                acc[r][1] = fmaf(x, wv.y, acc[r][1]);
                acc[r][2] = fmaf(x, wv.z, acc[r][2]);
                acc[r][3] = fmaf(x, wv.w, acc[r][3]);
            }
        }
    }

    float alv[4], arv[4];
#pragma unroll
    for (int i = 0; i < 4; ++i) { alv[i] = al[tc * 4 + i]; arv[i] = ar[tc * 4 + i]; }

#pragma unroll
    for (int r = 0; r < 4; ++r) {
        if (r0 + r >= n) continue;
        __half2 h01 = __floats2half2_rn(acc[r][0], acc[r][1]);
        __half2 h23 = __floats2half2_rn(acc[r][2], acc[r][3]);
        uint2 u = make_uint2(*(unsigned*)&h01, *(unsigned*)&h23);
        ((uint2*)(H2 + (size_t)(r0 + r) * HF))[tc] = u;
        float pl = acc[r][0] * alv[0] + acc[r][1] * alv[1] + acc[r][2] * alv[2] + acc[r][3] * alv[3];
        float pr = acc[r][0] * arv[0] + acc[r][1] * arv[1] + acc[r][2] * arv[2] + acc[r][3] * arv[3];
#pragma unroll
        for (int off = 1; off < 16; off <<= 1) {
            pl += __shfl_xor(pl, off);
            pr += __shfl_xor(pr, off);
        }
        if (tc == 0) { el[r0 + r] = pl; er[r0 + r] = pr; }
    }
}

// ---------------- Edge phase: softmax over incoming edges + aggregation ----------------
// Wave = 4 groups x 16 lanes; H rows fp16 (128B, 16 lanes x uint2).
// 32 edges/chunk (8 per group), 8 independent 8B gathers in flight.

__global__ __launch_bounds__(256)
void edge_kernel(const int* __restrict__ row_ptr, const int* __restrict__ ssrc,
                 const float* __restrict__ el, const float* __restrict__ er,
                 const __half* __restrict__ H2, const float* __restrict__ b,
                 float* __restrict__ Y, int n) {
    int wave = threadIdx.x >> 6, lane = threadIdx.x & 63;
    int node = blockIdx.x * 4 + wave;
    if (node >= n) return;
    int g = lane >> 4, fl = lane & 15;
    int s0 = row_ptr[node], s1 = row_ptr[node + 1];
    int d = s1 - s0;
    float ern = er[node];
    const uint2* H2v = (const uint2*)H2;

    if (d <= 64) {
        int sidx = 0;
        float e = -INFINITY;
        if (lane < d) {
            sidx = ssrc[s0 + lane];
            e = el[sidx] + ern;
            e = e > 0.f ? e : LEAKY * e;
        }
        float m = e;
#pragma unroll
        for (int off = 32; off; off >>= 1) m = fmaxf(m, __shfl_xor(m, off));
        float p = (lane < d) ? __expf(e - m) : 0.f;
        float psum = p;
#pragma unroll
        for (int off = 32; off; off >>= 1) psum += __shfl_xor(psum, off);

        float4 acc = make_float4(0.f, 0.f, 0.f, 0.f);
        int nchunk = (d + 31) >> 5;
        for (int c = 0; c < nchunk; ++c) {
            int jb = c * 32 + g;
            int ss[8];
            float pp[8];
#pragma unroll
            for (int u = 0; u < 8; ++u) {
                ss[u] = __shfl(sidx, jb + 4 * u);
                pp[u] = __shfl(p, jb + 4 * u);
            }
            uint2 vv[8];
#pragma unroll
            for (int u = 0; u < 8; ++u) vv[u] = H2v[(size_t)ss[u] * 16 + fl];
#pragma unroll
            for (int u = 0; u < 8; ++u) {
                __half2 a = *(__half2*)&vv[u].x;
                __half2 b2 = *(__half2*)&vv[u].y;
                float2 fa = __half22float2(a);
                float2 fb = __half22float2(b2);
                acc.x = fmaf(pp[u], fa.x, acc.x);
                acc.y = fmaf(pp[u], fa.y, acc.y);
                acc.z = fmaf(pp[u], fb.x, acc.z);
                acc.w = fmaf(pp[u], fb.y, acc.w);
            }
        }
#pragma unroll
        for (int off = 16; off <= 32; off <<= 1) {
            acc.x += __shfl_xor(acc.x, off);
            acc.y += __shfl_xor(acc.y, off);
            acc.z += __shfl_xor(acc.z, off);
            acc.w += __shfl_xor(acc.w, off);
        }
        float inv = d ? 1.f / psum : 0.f;
        float4 bv = ((const float4*)b)[fl];
        float4 o;
        o.x = fmaf(acc.x, inv, bv.x);
        o.y = fmaf(acc.y, inv, bv.y);
        o.z = fmaf(acc.z, inv, bv.z);
        o.w = fmaf(acc.w, inv, bv.w);
        o.x = o.x > 0.f ? o.x : 0.f;
        o.y = o.y > 0.f ? o.y : 0.f;
        o.z = o.z > 0.f ? o.z : 0.f;
        o.w = o.w > 0.f ? o.w : 0.f;
        if (g == 0) ((float4*)Y)[(size_t)node * 16 + fl] = o;
    } else {
        float m = -INFINITY;
        for (int j = s0 + lane; j < s1; j += 64) {
            float e = el[ssrc[j]] + ern;
            e = e > 0.f ? e : LEAKY * e;
            m = fmaxf(m, e);
        }
#pragma unroll
        for (int off = 32; off; off >>= 1) m = fmaxf(m, __shfl_xor(m, off));
        float acc = 0.f, psum = 0.f;
        for (int j = s0; j < s1; ++j) {
            int s = ssrc[j];
            float e = el[s] + ern;
            e = e > 0.f ? e : LEAKY * e;
            float p = __expf(e - m);
            psum += p;
            acc = fmaf(p, __half2float(H2[(size_t)s * HF + lane]), acc);
        }
        float o = acc / psum + b[lane];
        Y[(size_t)node * HF + lane] = o > 0.f ? o : 0.f;
    }
}

// ---------------- launch ----------------

extern "C" void kernel_launch(void* const* d_in, const int* in_sizes, int n_in,
                              void* d_out, int out_size, void* d_ws, size_t ws_size,
                              hipStream_t stream) {
    const int N = in_sizes[0] / 128;
    const int E = in_sizes[1];
    const int nb = (N + NPB - 1) >> 9;   // buckets (<= MAXNB for N <= 131072)

    const float* in_feat = (const float*)d_in[0];
    const int* src = (const int*)d_in[1];
    const int* dst = (const int*)d_in[2];
    const float* W1 = (const float*)d_in[3];
    const float* al1 = (const float*)d_in[4];
    const float* ar1 = (const float*)d_in[5];
    const float* b1 = (const float*)d_in[6];
    const float* W2 = (const float*)d_in[7];
    const float* al2 = (const float*)d_in[8];
    const float* ar2 = (const float*)d_in[9];
    const float* b2 = (const float*)d_in[10];
    const float* W3 = (const float*)d_in[11];
    const float* al3 = (const float*)d_in[12];
    const float* ar3 = (const float*)d_in[13];
    const float* b3 = (const float*)d_in[14];

    char* ws = (char*)d_ws;
    size_t off = 0;
    auto alloc = [&](size_t bytes) {
        void* p = ws + off;
        off += (bytes + 255) & ~(size_t)255;
        return p;
    };
    int* row_ptr = (int*)alloc(((size_t)N + 1) * 4);
    int* ssrc = (int*)alloc((size_t)E * 4);
    int2* part = (int2*)alloc((size_t)E * 8);
    int* Cmat = (int*)alloc((size_t)MAXNB * NBLK * 4);
    int* Omat = (int*)alloc((size_t)MAXNB * NBLK * 4);
    int* bbase = (int*)alloc(((size_t)MAXNB + 1) * 4);
    float* el = (float*)alloc((size_t)N * 4);
    float* er = (float*)alloc((size_t)N * 4);
    __half* H2buf = (__half*)alloc((size_t)N * HF * 2);
    float* Ybuf = (float*)alloc((size_t)N * HF * 4);

    part_count<<<NBLK, 256, 0, stream>>>(dst, Cmat, E, nb);
    scan_offsets<<<1, 256, 0, stream>>>(Cmat, Omat, bbase, E, nb);
    part_scatter<<<NBLK, 256, 0, stream>>>(src, dst, Omat, part, E, nb);
    bucket_csr<<<nb, NPB, 0, stream>>>(part, bbase, row_ptr, ssrc, N, E, nb);

    int gt = (N + 63) / 64;   // gemm tiles
    int ge = (N + 3) / 4;     // edge blocks (4 nodes/block)

    // layer 1
    gemm_kernel<128><<<gt, 256, 0, stream>>>(in_feat, W1, al1, ar1, H2buf, el, er, N);
    edge_kernel<<<ge, 256, 0, stream>>>(row_ptr, ssrc, el, er, H2buf, b1, Ybuf, N);
    // layer 2
    gemm_kernel<64><<<gt, 256, 0, stream>>>(Ybuf, W2, al2, ar2, H2buf, el, er, N);
    edge_kernel<<<ge, 256, 0, stream>>>(row_ptr, ssrc, el, er, H2buf, b2, Ybuf, N);
    // layer 3
    gemm_kernel<64><<<gt, 256, 0, stream>>>(Ybuf, W3, al3, ar3, H2buf, el, er, N);
    edge_kernel<<<ge, 256, 0, stream>>>(row_ptr, ssrc, el, er, H2buf, b3, (float*)d_out, N);
}

// Round 10
// 268.523 us; speedup vs baseline: 6.2779x; 1.0989x over previous
//
#include <hip/hip_runtime.h>
#include <hip/hip_fp16.h>
#include <math.h>

#define HF 64
#define LEAKY 0.2f
#define NBLK 256          // partition blocks
#define NPB 512           // nodes per bucket (bucket = dst >> 9)
#define MAXNB 256         // static LDS sizing for bucket counters

// ---------------- CSR build: two-level bucket partition ----------------

__global__ __launch_bounds__(256)
void part_count(const int* __restrict__ dst, int* __restrict__ Cmat, int E, int nb) {
    __shared__ int lc[MAXNB];
    int tid = threadIdx.x;
    for (int t = tid; t < nb; t += 256) lc[t] = 0;
    __syncthreads();
    int chunk = (E + NBLK - 1) / NBLK;
    int b0 = blockIdx.x * chunk, b1 = min(b0 + chunk, E);
    for (int i = b0 + tid; i < b1; i += 256)
        atomicAdd(&lc[dst[i] >> 9], 1);
    __syncthreads();
    for (int t = tid; t < nb; t += 256) Cmat[t * NBLK + blockIdx.x] = lc[t];
}

__global__ __launch_bounds__(256)
void scan_offsets(const int* __restrict__ Cmat, int* __restrict__ Omat,
                  int* __restrict__ bbase, int E, int nb) {
    __shared__ int tot[256];
    int t = threadIdx.x;
    int s = 0;
    if (t < nb)
        for (int blk = 0; blk < NBLK; ++blk) s += Cmat[t * NBLK + blk];
    tot[t] = s;
    __syncthreads();
    for (int off = 1; off < 256; off <<= 1) {
        int u = (t >= off) ? tot[t - off] : 0;
        __syncthreads();
        tot[t] += u;
        __syncthreads();
    }
    int excl = tot[t] - s;
    if (t < nb) {
        bbase[t] = excl;
        int run = excl;
        for (int blk = 0; blk < NBLK; ++blk) {
            Omat[t * NBLK + blk] = run;
            run += Cmat[t * NBLK + blk];
        }
    }
    if (t == 0) bbase[nb] = E;
}

__global__ __launch_bounds__(256)
void part_scatter(const int* __restrict__ src, const int* __restrict__ dst,
                  const int* __restrict__ Omat, int2* __restrict__ part, int E, int nb) {
    __shared__ int ocur[MAXNB];
    int tid = threadIdx.x;
    for (int t = tid; t < nb; t += 256) ocur[t] = Omat[t * NBLK + blockIdx.x];
    __syncthreads();
    int chunk = (E + NBLK - 1) / NBLK;
    int b0 = blockIdx.x * chunk, b1 = min(b0 + chunk, E);
    for (int i = b0 + tid; i < b1; i += 256) {
        int s = src[i], d = dst[i];
        int pos = atomicAdd(&ocur[d >> 9], 1);
        part[pos] = make_int2(s, d);
    }
}

__global__ __launch_bounds__(NPB)
void bucket_csr(const int2* __restrict__ part, const int* __restrict__ bbase,
                int* __restrict__ row_ptr, int* __restrict__ ssrc, int N, int E, int nb) {
    int b = blockIdx.x, tid = threadIdx.x;
    int bstart = bbase[b], bend = bbase[b + 1];
    int nb0 = b << 9;
    __shared__ int cnt[NPB];
    cnt[tid] = 0;
    __syncthreads();
    for (int i = bstart + tid; i < bend; i += NPB)
        atomicAdd(&cnt[part[i].y & (NPB - 1)], 1);
    __syncthreads();
    int v = cnt[tid];
    for (int off = 1; off < NPB; off <<= 1) {
        int u = (tid >= off) ? cnt[tid - off] : 0;
        __syncthreads();
        cnt[tid] += u;
        __syncthreads();
    }
    int excl = cnt[tid] - v;
    int node = nb0 + tid;
    if (node < N) row_ptr[node] = bstart + excl;
    __syncthreads();
    cnt[tid] = bstart + excl;
    __syncthreads();
    for (int i = bstart + tid; i < bend; i += NPB) {
        int2 e = part[i];
        int slot = atomicAdd(&cnt[e.y & (NPB - 1)], 1);
        ssrc[slot] = e.x;
    }
    if (b == nb - 1 && tid == 0) row_ptr[N] = E;
}

// ---------------- GEMM: H2(fp16) = X @ W, el = H a_l, er = H a_r ----------------

template <int K>
__global__ __launch_bounds__(256)
void gemm_kernel(const float* __restrict__ X, const float* __restrict__ W,
                 const float* __restrict__ al, const float* __restrict__ ar,
                 __half* __restrict__ H2, float* __restrict__ el, float* __restrict__ er,
                 int n) {
    __shared__ float Ws[K * 64];   // [k][c], native layout
    __shared__ float Xs[64 * K];   // [row][k ^ ((row&7)<<2)]
    int tid = threadIdx.x;
    int r0blk = blockIdx.x * 64;
    constexpr int F4 = K / 4;

    {
        const float4* Wg = (const float4*)W;
        float4* Wl = (float4*)Ws;
#pragma unroll
        for (int i = 0; i < K / 16; ++i)
            Wl[tid + i * 256] = Wg[tid + i * 256];
    }
    {
        const float* Xg = X + (size_t)r0blk * K;
#pragma unroll
        for (int i = 0; i < K / 16; ++i) {
            int idx = tid + i * 256;
            int row = idx / F4, kk = idx % F4;
            float4 v = make_float4(0.f, 0.f, 0.f, 0.f);
            if (r0blk + row < n) v = *(const float4*)(Xg + (size_t)row * K + kk * 4);
            *(float4*)&Xs[row * K + ((kk * 4) ^ ((row & 7) << 2))] = v;
        }
    }
    __syncthreads();

    int tc = tid & 15, tr = tid >> 4;
    int r0 = r0blk + tr * 4;

    float acc[4][4] = {};

#pragma unroll 4
    for (int kq = 0; kq < K; kq += 4) {
        float4 xv[4];
#pragma unroll
        for (int r = 0; r < 4; ++r) {
            int row = tr * 4 + r;
            xv[r] = *(const float4*)&Xs[row * K + (kq ^ ((row & 7) << 2))];
        }
#pragma unroll
        for (int kk = 0; kk < 4; ++kk) {
            float4 wv = *(const float4*)&Ws[(kq + kk) * 64 + tc * 4];
#pragma unroll
            for (int r = 0; r < 4; ++r) {
                float x = kk == 0 ? xv[r].x : kk == 1 ? xv[r].y : kk == 2 ? xv[r].z : xv[r].w;
                acc[r][0] = fmaf(x, wv.x, acc[r][0]);
                acc[r][1] = fmaf(x, wv.y, acc[r][1]);
                acc[r][2] = fmaf(x, wv.z, acc[r][2]);
                acc[r][3] = fmaf(x, wv.w, acc[r][3]);
            }
        }
    }

    float alv[4], arv[4];
#pragma unroll
    for (int i = 0; i < 4; ++i) { alv[i] = al[tc * 4 + i]; arv[i] = ar[tc * 4 + i]; }

#pragma unroll
    for (int r = 0; r < 4; ++r) {
        if (r0 + r >= n) continue;
        __half2 h01 = __floats2half2_rn(acc[r][0], acc[r][1]);
        __half2 h23 = __floats2half2_rn(acc[r][2], acc[r][3]);
        uint2 u = make_uint2(*(unsigned*)&h01, *(unsigned*)&h23);
        ((uint2*)(H2 + (size_t)(r0 + r) * HF))[tc] = u;
        float pl = acc[r][0] * alv[0] + acc[r][1] * alv[1] + acc[r][2] * alv[2] + acc[r][3] * alv[3];
        float pr = acc[r][0] * arv[0] + acc[r][1] * arv[1] + acc[r][2] * arv[2] + acc[r][3] * arv[3];
#pragma unroll
        for (int off = 1; off < 16; off <<= 1) {
            pl += __shfl_xor(pl, off);
            pr += __shfl_xor(pr, off);
        }
        if (tc == 0) { el[r0 + r] = pl; er[r0 + r] = pr; }
    }
}

// ---------------- Edge phase ----------------
// Fallback: whole wave processes one node (any degree). Same as round-8 body.
__device__ __forceinline__
void node_fullwave(int node, const int* __restrict__ row_ptr, const int* __restrict__ ssrc,
                   const float* __restrict__ el, const float* __restrict__ er,
                   const uint2* __restrict__ H2v, const __half* __restrict__ H2,
                   float4 bv, const float* __restrict__ b, float* __restrict__ Y,
                   int lane, int g, int fl) {
    int s0 = row_ptr[node], s1 = row_ptr[node + 1];
    int d = s1 - s0;
    float ern = er[node];

    if (d <= 64) {
        int sidx = 0;
        float e = -INFINITY;
        if (lane < d) {
            sidx = ssrc[s0 + lane];
            e = el[sidx] + ern;
            e = e > 0.f ? e : LEAKY * e;
        }
        float m = e;
#pragma unroll
        for (int off = 32; off; off >>= 1) m = fmaxf(m, __shfl_xor(m, off));
        float p = (lane < d) ? __expf(e - m) : 0.f;
        float psum = p;
#pragma unroll
        for (int off = 32; off; off >>= 1) psum += __shfl_xor(psum, off);

        float4 acc = make_float4(0.f, 0.f, 0.f, 0.f);
        int nchunk = (d + 31) >> 5;
        for (int c = 0; c < nchunk; ++c) {
            int jb = c * 32 + g;
            int ss[8];
            float pp[8];
#pragma unroll
            for (int u = 0; u < 8; ++u) {
                ss[u] = __shfl(sidx, jb + 4 * u);
                pp[u] = __shfl(p, jb + 4 * u);
            }
            uint2 vv[8];
#pragma unroll
            for (int u = 0; u < 8; ++u) vv[u] = H2v[(size_t)ss[u] * 16 + fl];
#pragma unroll
            for (int u = 0; u < 8; ++u) {
                __half2 a = *(__half2*)&vv[u].x;
                __half2 b2 = *(__half2*)&vv[u].y;
                float2 fa = __half22float2(a);
                float2 fb = __half22float2(b2);
                acc.x = fmaf(pp[u], fa.x, acc.x);
                acc.y = fmaf(pp[u], fa.y, acc.y);
                acc.z = fmaf(pp[u], fb.x, acc.z);
                acc.w = fmaf(pp[u], fb.y, acc.w);
            }
        }
#pragma unroll
        for (int off = 16; off <= 32; off <<= 1) {
            acc.x += __shfl_xor(acc.x, off);
            acc.y += __shfl_xor(acc.y, off);
            acc.z += __shfl_xor(acc.z, off);
            acc.w += __shfl_xor(acc.w, off);
        }
        float inv = d ? 1.f / psum : 0.f;
        float4 o;
        o.x = fmaf(acc.x, inv, bv.x);
        o.y = fmaf(acc.y, inv, bv.y);
        o.z = fmaf(acc.z, inv, bv.z);
        o.w = fmaf(acc.w, inv, bv.w);
        o.x = o.x > 0.f ? o.x : 0.f;
        o.y = o.y > 0.f ? o.y : 0.f;
        o.z = o.z > 0.f ? o.z : 0.f;
        o.w = o.w > 0.f ? o.w : 0.f;
        if (g == 0) ((float4*)Y)[(size_t)node * 16 + fl] = o;
    } else {
        float m = -INFINITY;
        for (int j = s0 + lane; j < s1; j += 64) {
            float e = el[ssrc[j]] + ern;
            e = e > 0.f ? e : LEAKY * e;
            m = fmaxf(m, e);
        }
#pragma unroll
        for (int off = 32; off; off >>= 1) m = fmaxf(m, __shfl_xor(m, off));
        float acc = 0.f, psum = 0.f;
        for (int j = s0; j < s1; ++j) {
            int s = ssrc[j];
            float e = el[s] + ern;
            e = e > 0.f ? e : LEAKY * e;
            float p = __expf(e - m);
            psum += p;
            acc = fmaf(p, __half2float(H2[(size_t)s * HF + lane]), acc);
        }
        float o = acc / psum + b[lane];
        Y[(size_t)node * HF + lane] = o > 0.f ? o : 0.f;
    }
}

// Main edge kernel: TWO nodes per wave (half-wave each; covers deg<=32, i.e.
// ~all of Poisson(16)). Groups 0-1 aggregate node A, groups 2-3 node B: the
// same 8 gathers/lane now carry 32 useful edges (2x useful bytes in flight,
// half the per-node VALU). Adjacent nodes -> contiguous ssrc/el wave reads.
// Grid-stride over node pairs with 2048 persistent blocks.
__global__ __launch_bounds__(256)
void edge_kernel(const int* __restrict__ row_ptr, const int* __restrict__ ssrc,
                 const float* __restrict__ el, const float* __restrict__ er,
                 const __half* __restrict__ H2, const float* __restrict__ b,
                 float* __restrict__ Y, int n) {
    int wave = threadIdx.x >> 6, lane = threadIdx.x & 63;
    int half = lane >> 5, hl = lane & 31;
    int g = lane >> 4, fl = lane & 15;
    const uint2* H2v = (const uint2*)H2;
    float4 bv = ((const float4*)b)[fl];
    int npairs = (n + 1) >> 1;

    for (int pr = blockIdx.x * 4 + wave; pr < npairs; pr += gridDim.x * 4) {
        int nodeA = pr * 2;
        int myNode = nodeA + half;
        bool ok = myNode < n;
        int s0 = 0, d = 0;
        if (ok) {
            s0 = row_ptr[myNode];
            d = row_ptr[myNode + 1] - s0;
        }
        int dA = __shfl(d, 0), dB = __shfl(d, 32);

        if (dA <= 32 && dB <= 32) {
            float ern = ok ? er[myNode] : 0.f;
            int sidx = 0;
            float e = -INFINITY;
            if (hl < d) {
                sidx = ssrc[s0 + hl];
                e = el[sidx] + ern;
                e = e > 0.f ? e : LEAKY * e;
            }
            float m = e;
#pragma unroll
            for (int off = 16; off; off >>= 1) m = fmaxf(m, __shfl_xor(m, off));
            float p = (hl < d) ? __expf(e - m) : 0.f;
            float psum = p;
#pragma unroll
            for (int off = 16; off; off >>= 1) psum += __shfl_xor(psum, off);

            // aggregation: group g serves node half (g>>1); edge slots j = c*16 + 2u + (g&1)
            float4 acc = make_float4(0.f, 0.f, 0.f, 0.f);
            int dg = (g >> 1) ? dB : dA;
            int hbase = (g >> 1) << 5;
            int gpar = g & 1;
            int nch = (dg + 15) >> 4;   // 0 chunks if dg==0
            for (int c = 0; c < nch; ++c) {
                int ss[8];
                float pp[8];
#pragma unroll
                for (int u = 0; u < 8; ++u) {
                    int sl = hbase + c * 16 + 2 * u + gpar;
                    ss[u] = __shfl(sidx, sl);
                    pp[u] = __shfl(p, sl);
                }
                uint2 vv[8];
#pragma unroll
                for (int u = 0; u < 8; ++u) vv[u] = H2v[(size_t)ss[u] * 16 + fl];
#pragma unroll
                for (int u = 0; u < 8; ++u) {
                    __half2 a = *(__half2*)&vv[u].x;
                    __half2 b2 = *(__half2*)&vv[u].y;
                    float2 fa = __half22float2(a);
                    float2 fb = __half22float2(b2);
                    acc.x = fmaf(pp[u], fa.x, acc.x);
                    acc.y = fmaf(pp[u], fa.y, acc.y);
                    acc.z = fmaf(pp[u], fb.x, acc.z);
                    acc.w = fmaf(pp[u], fb.y, acc.w);
                }
            }
            // merge the node's two groups (lanes ^16)
            acc.x += __shfl_xor(acc.x, 16);
            acc.y += __shfl_xor(acc.y, 16);
            acc.z += __shfl_xor(acc.z, 16);
            acc.w += __shfl_xor(acc.w, 16);
            float inv = d ? 1.f / psum : 0.f;   // d/psum belong to this lane's half
            float4 o;
            o.x = fmaf(acc.x, inv, bv.x);
            o.y = fmaf(acc.y, inv, bv.y);
            o.z = fmaf(acc.z, inv, bv.z);
            o.w = fmaf(acc.w, inv, bv.w);
            o.x = o.x > 0.f ? o.x : 0.f;
            o.y = o.y > 0.f ? o.y : 0.f;
            o.z = o.z > 0.f ? o.z : 0.f;
            o.w = o.w > 0.f ? o.w : 0.f;
            if (!(g & 1) && ok) ((float4*)Y)[(size_t)myNode * 16 + fl] = o;
        } else {
            node_fullwave(nodeA, row_ptr, ssrc, el, er, H2v, H2, bv, b, Y, lane, g, fl);
            if (nodeA + 1 < n)
                node_fullwave(nodeA + 1, row_ptr, ssrc, el, er, H2v, H2, bv, b, Y, lane, g, fl);
        }
    }
}

// ---------------- launch ----------------

extern "C" void kernel_launch(void* const* d_in, const int* in_sizes, int n_in,
                              void* d_out, int out_size, void* d_ws, size_t ws_size,
                              hipStream_t stream) {
    const int N = in_sizes[0] / 128;
    const int E = in_sizes[1];
    const int nb = (N + NPB - 1) >> 9;

    const float* in_feat = (const float*)d_in[0];
    const int* src = (const int*)d_in[1];
    const int* dst = (const int*)d_in[2];
    const float* W1 = (const float*)d_in[3];
    const float* al1 = (const float*)d_in[4];
    const float* ar1 = (const float*)d_in[5];
    const float* b1 = (const float*)d_in[6];
    const float* W2 = (const float*)d_in[7];
    const float* al2 = (const float*)d_in[8];
    const float* ar2 = (const float*)d_in[9];
    const float* b2 = (const float*)d_in[10];
    const float* W3 = (const float*)d_in[11];
    const float* al3 = (const float*)d_in[12];
    const float* ar3 = (const float*)d_in[13];
    const float* b3 = (const float*)d_in[14];

    char* ws = (char*)d_ws;
    size_t off = 0;
    auto alloc = [&](size_t bytes) {
        void* p = ws + off;
        off += (bytes + 255) & ~(size_t)255;
        return p;
    };
    int* row_ptr = (int*)alloc(((size_t)N + 1) * 4);
    int* ssrc = (int*)alloc((size_t)E * 4);
    int2* part = (int2*)alloc((size_t)E * 8);
    int* Cmat = (int*)alloc((size_t)MAXNB * NBLK * 4);
    int* Omat = (int*)alloc((size_t)MAXNB * NBLK * 4);
    int* bbase = (int*)alloc(((size_t)MAXNB + 1) * 4);
    float* el = (float*)alloc((size_t)N * 4);
    float* er = (float*)alloc((size_t)N * 4);
    __half* H2buf = (__half*)alloc((size_t)N * HF * 2);
    float* Ybuf = (float*)alloc((size_t)N * HF * 4);

    part_count<<<NBLK, 256, 0, stream>>>(dst, Cmat, E, nb);
    scan_offsets<<<1, 256, 0, stream>>>(Cmat, Omat, bbase, E, nb);
    part_scatter<<<NBLK, 256, 0, stream>>>(src, dst, Omat, part, E, nb);
    bucket_csr<<<nb, NPB, 0, stream>>>(part, bbase, row_ptr, ssrc, N, E, nb);

    int gt = (N + 63) / 64;   // gemm tiles
    int ge = 2048;            // persistent edge blocks (grid-stride over pairs)

    // layer 1
    gemm_kernel<128><<<gt, 256, 0, stream>>>(in_feat, W1, al1, ar1, H2buf, el, er, N);
    edge_kernel<<<ge, 256, 0, stream>>>(row_ptr, ssrc, el, er, H2buf, b1, Ybuf, N);
    // layer 2
    gemm_kernel<64><<<gt, 256, 0, stream>>>(Ybuf, W2, al2, ar2, H2buf, el, er, N);
    edge_kernel<<<ge, 256, 0, stream>>>(row_ptr, ssrc, el, er, H2buf, b2, Ybuf, N);
    // layer 3
    gemm_kernel<64><<<gt, 256, 0, stream>>>(Ybuf, W3, al3, ar3, H2buf, el, er, N);
    edge_kernel<<<ge, 256, 0, stream>>>(row_ptr, ssrc, el, er, H2buf, b3, (float*)d_out, N);
}

// Round 11
// 264.997 us; speedup vs baseline: 6.3614x; 1.0133x over previous
//
#include <hip/hip_runtime.h>
#include <hip/hip_fp16.h>
#include <math.h>

#define HF 64
#define LEAKY 0.2f
#define NBLK 256          // partition blocks
#define NPB 512           // nodes per bucket (bucket = dst >> 9)
#define MAXNB 256         // static LDS sizing for bucket counters

typedef _Float16 f16x2 __attribute__((ext_vector_type(2)));

__device__ __forceinline__ float dot2f(f16x2 a, f16x2 b, float c) {
#if __has_builtin(__builtin_amdgcn_fdot2)
    return __builtin_amdgcn_fdot2(a, b, c, false);
#else
    return fmaf((float)a[0], (float)b[0], fmaf((float)a[1], (float)b[1], c));
#endif
}

// ---------------- CSR build: two-level bucket partition ----------------

__global__ __launch_bounds__(256)
void part_count(const int* __restrict__ dst, int* __restrict__ Cmat, int E, int nb) {
    __shared__ int lc[MAXNB];
    int tid = threadIdx.x;
    for (int t = tid; t < nb; t += 256) lc[t] = 0;
    __syncthreads();
    int chunk = (E + NBLK - 1) / NBLK;
    int b0 = blockIdx.x * chunk, b1 = min(b0 + chunk, E);
    for (int i = b0 + tid; i < b1; i += 256)
        atomicAdd(&lc[dst[i] >> 9], 1);
    __syncthreads();
    for (int t = tid; t < nb; t += 256) Cmat[t * NBLK + blockIdx.x] = lc[t];
}

__global__ __launch_bounds__(256)
void scan_offsets(const int* __restrict__ Cmat, int* __restrict__ Omat,
                  int* __restrict__ bbase, int E, int nb) {
    __shared__ int tot[256];
    int t = threadIdx.x;
    int s = 0;
    if (t < nb)
        for (int blk = 0; blk < NBLK; ++blk) s += Cmat[t * NBLK + blk];
    tot[t] = s;
    __syncthreads();
    for (int off = 1; off < 256; off <<= 1) {
        int u = (t >= off) ? tot[t - off] : 0;
        __syncthreads();
        tot[t] += u;
        __syncthreads();
    }
    int excl = tot[t] - s;
    if (t < nb) {
        bbase[t] = excl;
        int run = excl;
        for (int blk = 0; blk < NBLK; ++blk) {
            Omat[t * NBLK + blk] = run;
            run += Cmat[t * NBLK + blk];
        }
    }
    if (t == 0) bbase[nb] = E;
}

__global__ __launch_bounds__(256)
void part_scatter(const int* __restrict__ src, const int* __restrict__ dst,
                  const int* __restrict__ Omat, int2* __restrict__ part, int E, int nb) {
    __shared__ int ocur[MAXNB];
    int tid = threadIdx.x;
    for (int t = tid; t < nb; t += 256) ocur[t] = Omat[t * NBLK + blockIdx.x];
    __syncthreads();
    int chunk = (E + NBLK - 1) / NBLK;
    int b0 = blockIdx.x * chunk, b1 = min(b0 + chunk, E);
    for (int i = b0 + tid; i < b1; i += 256) {
        int s = src[i], d = dst[i];
        int pos = atomicAdd(&ocur[d >> 9], 1);
        part[pos] = make_int2(s, d);
    }
}

__global__ __launch_bounds__(NPB)
void bucket_csr(const int2* __restrict__ part, const int* __restrict__ bbase,
                int* __restrict__ row_ptr, int* __restrict__ ssrc, int N, int E, int nb) {
    int b = blockIdx.x, tid = threadIdx.x;
    int bstart = bbase[b], bend = bbase[b + 1];
    int nb0 = b << 9;
    __shared__ int cnt[NPB];
    cnt[tid] = 0;
    __syncthreads();
    for (int i = bstart + tid; i < bend; i += NPB)
        atomicAdd(&cnt[part[i].y & (NPB - 1)], 1);
    __syncthreads();
    int v = cnt[tid];
    for (int off = 1; off < NPB; off <<= 1) {
        int u = (tid >= off) ? cnt[tid - off] : 0;
        __syncthreads();
        cnt[tid] += u;
        __syncthreads();
    }
    int excl = cnt[tid] - v;
    int node = nb0 + tid;
    if (node < N) row_ptr[node] = bstart + excl;
    __syncthreads();
    cnt[tid] = bstart + excl;
    __syncthreads();
    for (int i = bstart + tid; i < bend; i += NPB) {
        int2 e = part[i];
        int slot = atomicAdd(&cnt[e.y & (NPB - 1)], 1);
        ssrc[slot] = e.x;
    }
    if (b == nb - 1 && tid == 0) row_ptr[N] = E;
}

// ---------------- GEMM: H2(fp16) = X @ W, el = H a_l, er = H a_r ----------------
// fp16 LDS tiles + v_dot2_f32_f16, f32 accumulate. LDS = 32KB (K=128) /
// 16KB (K=64) -> 5 / 8 blocks per CU (was 64KB -> 2, latency-bound at 17% occ).
// Wh: [k2][c] half2 packing (W[2k][c], W[2k+1][c]) -> b128 col reads, 2-way free.
// Xh: [row][k2 ^ ((row&15)<<1)] -> b64 pair reads hit 4 distinct banks across tr.

template <int K>
__global__ __launch_bounds__(256)
void gemm_kernel(const float* __restrict__ X, const float* __restrict__ W,
                 const float* __restrict__ al, const float* __restrict__ ar,
                 __half* __restrict__ H2, float* __restrict__ el, float* __restrict__ er,
                 int n) {
    constexpr int K2 = K / 2;
    __shared__ f16x2 Wh[K2 * 64];
    __shared__ f16x2 Xh[64 * K2];
    int tid = threadIdx.x;
    int r0blk = blockIdx.x * 64;

    // stage W: pack (W[2k2][c], W[2k2+1][c]); coalesced 256B row reads; RN casts
    for (int idx = tid; idx < K2 * 64; idx += 256) {
        int k2 = idx >> 6, c = idx & 63;
        f16x2 h;
        h[0] = (_Float16)W[(2 * k2) * 64 + c];
        h[1] = (_Float16)W[(2 * k2 + 1) * 64 + c];
        Wh[idx] = h;
    }
    // stage X: coalesced float4 reads; write 2 swizzled half2 per float4
    const float* Xg = X + (size_t)r0blk * K;
    for (int idx = tid; idx < 64 * (K / 4); idx += 256) {
        int row = idx / (K / 4), k4 = idx % (K / 4);
        float4 v = make_float4(0.f, 0.f, 0.f, 0.f);
        if (r0blk + row < n) v = *(const float4*)(Xg + (size_t)row * K + k4 * 4);
        f16x2 h0, h1;
        h0[0] = (_Float16)v.x; h0[1] = (_Float16)v.y;
        h1[0] = (_Float16)v.z; h1[1] = (_Float16)v.w;
        int sw = (row & 15) << 1;
        Xh[row * K2 + ((2 * k4) ^ sw)] = h0;
        Xh[row * K2 + ((2 * k4 + 1) ^ sw)] = h1;
    }
    __syncthreads();

    int tc = tid & 15, tr = tid >> 4;
    int r0 = r0blk + tr * 4;
    float acc[4][4] = {};

#pragma unroll 4
    for (int k2 = 0; k2 < K2; k2 += 2) {
        f16x2 xa[4], xb[4];
#pragma unroll
        for (int r = 0; r < 4; ++r) {
            int row = tr * 4 + r;
            int sw = (row & 15) << 1;           // bit0 preserved -> pair contiguous
            const f16x2* p = &Xh[row * K2 + (k2 ^ sw)];
            xa[r] = p[0];
            xb[r] = p[1];
        }
        const f16x2* w0 = &Wh[k2 * 64 + tc * 4];
        const f16x2* w1 = &Wh[(k2 + 1) * 64 + tc * 4];
#pragma unroll
        for (int i = 0; i < 4; ++i) {
            f16x2 wv0 = w0[i], wv1 = w1[i];
#pragma unroll
            for (int r = 0; r < 4; ++r) {
                acc[r][i] = dot2f(xa[r], wv0, acc[r][i]);
                acc[r][i] = dot2f(xb[r], wv1, acc[r][i]);
            }
        }
    }

    float alv[4], arv[4];
#pragma unroll
    for (int i = 0; i < 4; ++i) { alv[i] = al[tc * 4 + i]; arv[i] = ar[tc * 4 + i]; }

#pragma unroll
    for (int r = 0; r < 4; ++r) {
        if (r0 + r >= n) continue;
        __half2 h01 = __floats2half2_rn(acc[r][0], acc[r][1]);
        __half2 h23 = __floats2half2_rn(acc[r][2], acc[r][3]);
        uint2 u = make_uint2(*(unsigned*)&h01, *(unsigned*)&h23);
        ((uint2*)(H2 + (size_t)(r0 + r) * HF))[tc] = u;
        float pl = acc[r][0] * alv[0] + acc[r][1] * alv[1] + acc[r][2] * alv[2] + acc[r][3] * alv[3];
        float pr = acc[r][0] * arv[0] + acc[r][1] * arv[1] + acc[r][2] * arv[2] + acc[r][3] * arv[3];
#pragma unroll
        for (int off = 1; off < 16; off <<= 1) {
            pl += __shfl_xor(pl, off);
            pr += __shfl_xor(pr, off);
        }
        if (tc == 0) { el[r0 + r] = pl; er[r0 + r] = pr; }
    }
}

// ---------------- Edge phase ----------------
__device__ __forceinline__
void node_fullwave(int node, const int* __restrict__ row_ptr, const int* __restrict__ ssrc,
                   const float* __restrict__ el, const float* __restrict__ er,
                   const uint2* __restrict__ H2v, const __half* __restrict__ H2,
                   float4 bv, const float* __restrict__ b, float* __restrict__ Y,
                   int lane, int g, int fl) {
    int s0 = row_ptr[node], s1 = row_ptr[node + 1];
    int d = s1 - s0;
    float ern = er[node];

    if (d <= 64) {
        int sidx = 0;
        float e = -INFINITY;
        if (lane < d) {
            sidx = ssrc[s0 + lane];
            e = el[sidx] + ern;
            e = e > 0.f ? e : LEAKY * e;
        }
        float m = e;
#pragma unroll
        for (int off = 32; off; off >>= 1) m = fmaxf(m, __shfl_xor(m, off));
        float p = (lane < d) ? __expf(e - m) : 0.f;
        float psum = p;
#pragma unroll
        for (int off = 32; off; off >>= 1) psum += __shfl_xor(psum, off);

        float4 acc = make_float4(0.f, 0.f, 0.f, 0.f);
        int nchunk = (d + 31) >> 5;
        for (int c = 0; c < nchunk; ++c) {
            int jb = c * 32 + g;
            int ss[8];
            float pp[8];
#pragma unroll
            for (int u = 0; u < 8; ++u) {
                ss[u] = __shfl(sidx, jb + 4 * u);
                pp[u] = __shfl(p, jb + 4 * u);
            }
            uint2 vv[8];
#pragma unroll
            for (int u = 0; u < 8; ++u) vv[u] = H2v[(size_t)ss[u] * 16 + fl];
#pragma unroll
            for (int u = 0; u < 8; ++u) {
                __half2 a = *(__half2*)&vv[u].x;
                __half2 b2 = *(__half2*)&vv[u].y;
                float2 fa = __half22float2(a);
                float2 fb = __half22float2(b2);
                acc.x = fmaf(pp[u], fa.x, acc.x);
                acc.y = fmaf(pp[u], fa.y, acc.y);
                acc.z = fmaf(pp[u], fb.x, acc.z);
                acc.w = fmaf(pp[u], fb.y, acc.w);
            }
        }
#pragma unroll
        for (int off = 16; off <= 32; off <<= 1) {
            acc.x += __shfl_xor(acc.x, off);
            acc.y += __shfl_xor(acc.y, off);
            acc.z += __shfl_xor(acc.z, off);
            acc.w += __shfl_xor(acc.w, off);
        }
        float inv = d ? 1.f / psum : 0.f;
        float4 o;
        o.x = fmaf(acc.x, inv, bv.x);
        o.y = fmaf(acc.y, inv, bv.y);
        o.z = fmaf(acc.z, inv, bv.z);
        o.w = fmaf(acc.w, inv, bv.w);
        o.x = o.x > 0.f ? o.x : 0.f;
        o.y = o.y > 0.f ? o.y : 0.f;
        o.z = o.z > 0.f ? o.z : 0.f;
        o.w = o.w > 0.f ? o.w : 0.f;
        if (g == 0) ((float4*)Y)[(size_t)node * 16 + fl] = o;
    } else {
        float m = -INFINITY;
        for (int j = s0 + lane; j < s1; j += 64) {
            float e = el[ssrc[j]] + ern;
            e = e > 0.f ? e : LEAKY * e;
            m = fmaxf(m, e);
        }
#pragma unroll
        for (int off = 32; off; off >>= 1) m = fmaxf(m, __shfl_xor(m, off));
        float acc = 0.f, psum = 0.f;
        for (int j = s0; j < s1; ++j) {
            int s = ssrc[j];
            float e = el[s] + ern;
            e = e > 0.f ? e : LEAKY * e;
            float p = __expf(e - m);
            psum += p;
            acc = fmaf(p, __half2float(H2[(size_t)s * HF + lane]), acc);
        }
        float o = acc / psum + b[lane];
        Y[(size_t)node * HF + lane] = o > 0.f ? o : 0.f;
    }
}

// Two nodes per wave (half-wave each); groups 0-1 node A, 2-3 node B.
__global__ __launch_bounds__(256)
void edge_kernel(const int* __restrict__ row_ptr, const int* __restrict__ ssrc,
                 const float* __restrict__ el, const float* __restrict__ er,
                 const __half* __restrict__ H2, const float* __restrict__ b,
                 float* __restrict__ Y, int n) {
    int wave = threadIdx.x >> 6, lane = threadIdx.x & 63;
    int half = lane >> 5, hl = lane & 31;
    int g = lane >> 4, fl = lane & 15;
    const uint2* H2v = (const uint2*)H2;
    float4 bv = ((const float4*)b)[fl];
    int npairs = (n + 1) >> 1;

    for (int pr = blockIdx.x * 4 + wave; pr < npairs; pr += gridDim.x * 4) {
        int nodeA = pr * 2;
        int myNode = nodeA + half;
        bool ok = myNode < n;
        int s0 = 0, d = 0;
        if (ok) {
            s0 = row_ptr[myNode];
            d = row_ptr[myNode + 1] - s0;
        }
        int dA = __shfl(d, 0), dB = __shfl(d, 32);

        if (dA <= 32 && dB <= 32) {
            float ern = ok ? er[myNode] : 0.f;
            int sidx = 0;
            float e = -INFINITY;
            if (hl < d) {
                sidx = ssrc[s0 + hl];
                e = el[sidx] + ern;
                e = e > 0.f ? e : LEAKY * e;
            }
            float m = e;
#pragma unroll
            for (int off = 16; off; off >>= 1) m = fmaxf(m, __shfl_xor(m, off));
            float p = (hl < d) ? __expf(e - m) : 0.f;
            float psum = p;
#pragma unroll
            for (int off = 16; off; off >>= 1) psum += __shfl_xor(psum, off);

            float4 acc = make_float4(0.f, 0.f, 0.f, 0.f);
            int dg = (g >> 1) ? dB : dA;
            int hbase = (g >> 1) << 5;
            int gpar = g & 1;
            int nch = (dg + 15) >> 4;
            for (int c = 0; c < nch; ++c) {
                int ss[8];
                float pp[8];
#pragma unroll
                for (int u = 0; u < 8; ++u) {
                    int sl = hbase + c * 16 + 2 * u + gpar;
                    ss[u] = __shfl(sidx, sl);
                    pp[u] = __shfl(p, sl);
                }
                uint2 vv[8];
#pragma unroll
                for (int u = 0; u < 8; ++u) vv[u] = H2v[(size_t)ss[u] * 16 + fl];
#pragma unroll
                for (int u = 0; u < 8; ++u) {
                    __half2 a = *(__half2*)&vv[u].x;
                    __half2 b2 = *(__half2*)&vv[u].y;
                    float2 fa = __half22float2(a);
                    float2 fb = __half22float2(b2);
                    acc.x = fmaf(pp[u], fa.x, acc.x);
                    acc.y = fmaf(pp[u], fa.y, acc.y);
                    acc.z = fmaf(pp[u], fb.x, acc.z);
                    acc.w = fmaf(pp[u], fb.y, acc.w);
                }
            }
            acc.x += __shfl_xor(acc.x, 16);
            acc.y += __shfl_xor(acc.y, 16);
            acc.z += __shfl_xor(acc.z, 16);
            acc.w += __shfl_xor(acc.w, 16);
            float inv = d ? 1.f / psum : 0.f;
            float4 o;
            o.x = fmaf(acc.x, inv, bv.x);
            o.y = fmaf(acc.y, inv, bv.y);
            o.z = fmaf(acc.z, inv, bv.z);
            o.w = fmaf(acc.w, inv, bv.w);
            o.x = o.x > 0.f ? o.x : 0.f;
            o.y = o.y > 0.f ? o.y : 0.f;
            o.z = o.z > 0.f ? o.z : 0.f;
            o.w = o.w > 0.f ? o.w : 0.f;
            if (!(g & 1) && ok) ((float4*)Y)[(size_t)myNode * 16 + fl] = o;
        } else {
            node_fullwave(nodeA, row_ptr, ssrc, el, er, H2v, H2, bv, b, Y, lane, g, fl);
            if (nodeA + 1 < n)
                node_fullwave(nodeA + 1, row_ptr, ssrc, el, er, H2v, H2, bv, b, Y, lane, g, fl);
        }
    }
}

// ---------------- launch ----------------

extern "C" void kernel_launch(void* const* d_in, const int* in_sizes, int n_in,
                              void* d_out, int out_size, void* d_ws, size_t ws_size,
                              hipStream_t stream) {
    const int N = in_sizes[0] / 128;
    const int E = in_sizes[1];
    const int nb = (N + NPB - 1) >> 9;

    const float* in_feat = (const float*)d_in[0];
    const int* src = (const int*)d_in[1];
    const int* dst = (const int*)d_in[2];
    const float* W1 = (const float*)d_in[3];
    const float* al1 = (const float*)d_in[4];
    const float* ar1 = (const float*)d_in[5];
    const float* b1 = (const float*)d_in[6];
    const float* W2 = (const float*)d_in[7];
    const float* al2 = (const float*)d_in[8];
    const float* ar2 = (const float*)d_in[9];
    const float* b2 = (const float*)d_in[10];
    const float* W3 = (const float*)d_in[11];
    const float* al3 = (const float*)d_in[12];
    const float* ar3 = (const float*)d_in[13];
    const float* b3 = (const float*)d_in[14];

    char* ws = (char*)d_ws;
    size_t off = 0;
    auto alloc = [&](size_t bytes) {
        void* p = ws + off;
        off += (bytes + 255) & ~(size_t)255;
        return p;
    };
    int* row_ptr = (int*)alloc(((size_t)N + 1) * 4);
    int* ssrc = (int*)alloc((size_t)E * 4);
    int2* part = (int2*)alloc((size_t)E * 8);
    int* Cmat = (int*)alloc((size_t)MAXNB * NBLK * 4);
    int* Omat = (int*)alloc((size_t)MAXNB * NBLK * 4);
    int* bbase = (int*)alloc(((size_t)MAXNB + 1) * 4);
    float* el = (float*)alloc((size_t)N * 4);
    float* er = (float*)alloc((size_t)N * 4);
    __half* H2buf = (__half*)alloc((size_t)N * HF * 2);
    float* Ybuf = (float*)alloc((size_t)N * HF * 4);

    part_count<<<NBLK, 256, 0, stream>>>(dst, Cmat, E, nb);
    scan_offsets<<<1, 256, 0, stream>>>(Cmat, Omat, bbase, E, nb);
    part_scatter<<<NBLK, 256, 0, stream>>>(src, dst, Omat, part, E, nb);
    bucket_csr<<<nb, NPB, 0, stream>>>(part, bbase, row_ptr, ssrc, N, E, nb);

    int gt = (N + 63) / 64;   // gemm tiles
    int ge = 2048;            // persistent edge blocks

    // layer 1
    gemm_kernel<128><<<gt, 256, 0, stream>>>(in_feat, W1, al1, ar1, H2buf, el, er, N);
    edge_kernel<<<ge, 256, 0, stream>>>(row_ptr, ssrc, el, er, H2buf, b1, Ybuf, N);
    // layer 2
    gemm_kernel<64><<<gt, 256, 0, stream>>>(Ybuf, W2, al2, ar2, H2buf, el, er, N);
    edge_kernel<<<ge, 256, 0, stream>>>(row_ptr, ssrc, el, er, H2buf, b2, Ybuf, N);
    // layer 3
    gemm_kernel<64><<<gt, 256, 0, stream>>>(Ybuf, W3, al3, ar3, H2buf, el, er, N);
    edge_kernel<<<ge, 256, 0, stream>>>(row_ptr, ssrc, el, er, H2buf, b3, (float*)d_out, N);
}